// Round 7
// baseline (1501.274 us; speedup 1.0000x reference)
//
#include <hip/hip_runtime.h>
#include <cmath>

typedef unsigned char u8;
typedef unsigned short u16;
typedef unsigned int u32;
typedef __attribute__((ext_vector_type(8))) short s8v;    // 8 bf16 = 4 VGPRs
typedef __attribute__((ext_vector_type(4))) float f32x4;  // MFMA acc

#define B 256
#define F 128
#define Q 4096
#define E 128
#define QW 128               // Q/32 words per row
#define INV_TAU 5.0f
#define CAP 256              // compact entries per (e,b); binomial(4096,1/32) max ~180

// ---- ws layout (offsets in floats) ----
#define W_SCORES 0u            // B*Q = 1048576
#define W_CNT    1048576u      // B*Q
#define W_UNC    2097152u      // 4096
#define W_CNTB   2101248u      // E*B ints = 32768
#define W_RSUM   2134016u      // E*B floats = 32768
#define W_NLSE   2166784u      // 256
#define W_MOCO   2167040u
#define W_EASY   2167296u
#define W_HARD   2167552u
#define W_UB     2167808u      // 256 pad
#define W_INVN   2168064u      // E*Q = 524288
#define W_AF     2692352u      // bf16 E*B*F -> 2097152 floats
#define W_PB     4789504u      // packed boot  E*QW*B words = 4194304
#define W_PS     8983808u      // packed smask E*QW*B words = 4194304
#define W_PN     13178112u     // packed mask_n E*QW*F words = 2097152
#define W_ENT    15275264u     // Ec*256*CAP uint2 -> Ec*131072 floats
#define NZERO    2166784u      // zero range: SCORES..RSUM end = 2116*1024

// ---- out layout (floats) ----
#define O_MOCO   0u
#define O_LOGITS 1u            // (B, Q+1)
#define O_ELOSS  1048833u
#define O_EMASK  1048834u      // (B, Q)
#define O_HLOSS  2097410u
#define O_HMASK  2097411u      // (B, Q)

static __device__ __forceinline__ u16 f2bf(float x) {
    unsigned int u = __builtin_bit_cast(unsigned int, x);
    unsigned int r = (u + 0x7FFFu + ((u >> 16) & 1u)) >> 16;
    return (u16)r;
}

__global__ void k_zero(float4* __restrict__ p) {
    p[(size_t)blockIdx.x * 256 + threadIdx.x] = make_float4(0.f, 0.f, 0.f, 0.f);
}

// ---- bit-pack all three masks; z selects tensor. out[e][qw][r] transposed words.
__global__ void __launch_bounds__(256) k_pack(const u8* __restrict__ boot,
                                              const u8* __restrict__ smask,
                                              const u8* __restrict__ maskn,
                                              u32* __restrict__ pb, u32* __restrict__ ps,
                                              u32* __restrict__ pn) {
    int z = blockIdx.z;
    int Rin = (z == 2) ? F : B;
    if (z == 2 && blockIdx.x >= 2048) return;
    const u8* in = (z == 0) ? boot : (z == 1) ? smask : maskn;
    u32* out = (z == 0) ? pb : (z == 1) ? ps : pn;
    __shared__ u32 lds[64 * 133];
    int t = threadIdx.x;
    int r0 = blockIdx.x * 64;
    int q0 = blockIdx.y * 512;
    int qw0 = q0 >> 5;
    #pragma unroll
    for (int i = 0; i < 8; i++) {
        int w = i * 256 + t;
        int row = w >> 5, c = w & 31;
        uint4 v = *(const uint4*)&in[(size_t)(r0 + row) * Q + q0 + c * 16];
        int base = row * 133 + c * 4;
        lds[base] = v.x; lds[base + 1] = v.y; lds[base + 2] = v.z; lds[base + 3] = v.w;
    }
    __syncthreads();
    int e = r0 / Rin, rr = r0 % Rin;
    #pragma unroll
    for (int k = 0; k < 4; k++) {
        int qw = (t >> 6) + k * 4;
        int r = t & 63;
        u32 w = 0;
        #pragma unroll
        for (int j = 0; j < 8; j++) {
            u32 u = lds[r * 133 + qw * 8 + j];
            w |= ((u & 1u) | ((u >> 7) & 2u) | ((u >> 14) & 4u) | ((u >> 21) & 8u)) << (j * 4);
        }
        out[((size_t)e * QW + qw0 + qw) * Rin + rr + r] = w;
    }
}

// one block (128 thr) per (e,b): masked l2-norm of teacher row -> bf16 A-fragments
__global__ void k_afrag(const float* __restrict__ teacher, const u8* __restrict__ mask_t,
                        u16* __restrict__ af) {
    int eb = blockIdx.x;
    int e  = eb >> 8;
    int b  = eb & (B - 1);
    int f  = threadIdx.x;
    float v = mask_t[(size_t)eb * F + f] ? 0.f : teacher[b * F + f];
    float ss = v * v;
    #pragma unroll
    for (int o = 32; o > 0; o >>= 1) ss += __shfl_down(ss, o);
    __shared__ float s2[2];
    if ((threadIdx.x & 63) == 0) s2[threadIdx.x >> 6] = ss;
    __syncthreads();
    float d = fmaxf(sqrtf(s2[0] + s2[1]), 1e-12f);
    float t = v / d;
    int bg = b >> 4, m = b & 15;
    int kb = f >> 5, quad = (f >> 3) & 3, j = f & 7;
    int lane = quad * 16 + m;
    af[((((size_t)e * 16 + bg) * 4 + kb) * 64 + lane) * 8 + j] = f2bf(t);
}

// per (e, 1024-q block): 1/(TAU*||masked neg col||)
__global__ void __launch_bounds__(256) k_invn(const float* __restrict__ neg,
                                              const u32* __restrict__ pn,
                                              float* __restrict__ invn) {
    __shared__ u32 lds[32 * 128];
    int e = blockIdx.x, t = threadIdx.x;
    int qblk = blockIdx.y;
    size_t base = ((size_t)e * QW + qblk * 32) * F;
    #pragma unroll
    for (int k = 0; k < 16; k++) lds[t + 256 * k] = pn[base + t + 256 * k];
    __syncthreads();
    int q0 = qblk * 1024 + t * 4;
    int qwl = (t * 4) >> 5;
    int sh = (t * 4) & 31;
    float s0 = 0.f, s1 = 0.f, s2 = 0.f, s3 = 0.f;
    #pragma unroll 4
    for (int f = 0; f < F; f++) {
        float4 v = *(const float4*)&neg[(size_t)f * Q + q0];
        u32 w = lds[qwl * 128 + f] >> sh;
        if (!(w & 1u)) s0 = fmaf(v.x, v.x, s0);
        if (!(w & 2u)) s1 = fmaf(v.y, v.y, s1);
        if (!(w & 4u)) s2 = fmaf(v.z, v.z, s2);
        if (!(w & 8u)) s3 = fmaf(v.w, v.w, s3);
    }
    float4 r;
    r.x = INV_TAU / fmaxf(sqrtf(s0), 1e-12f);
    r.y = INV_TAU / fmaxf(sqrtf(s1), 1e-12f);
    r.z = INV_TAU / fmaxf(sqrtf(s2), 1e-12f);
    r.w = INV_TAU / fmaxf(sqrtf(s3), 1e-12f);
    *(float4*)&invn[(size_t)e * Q + q0] = r;
}

// Fused: per (e, 64-q slab): B-frags inline, MFMA, exp in place, column softmax+
// entropy (boot), per-row smask exp-sum partials -> rsum, popc extraction of (q, exp).
__global__ void __launch_bounds__(256) k_fused(
        const u16* __restrict__ af, const float* __restrict__ neg,
        const u32* __restrict__ pn, const float* __restrict__ invn,
        const u32* __restrict__ pb, const u32* __restrict__ ps,
        float* __restrict__ unc, uint2* __restrict__ ent_buf,
        int* __restrict__ cnt_buf, float* __restrict__ rsum, int e0) {
    __shared__ u16 bfrag[4][4][512];                          // 16 KB
    __shared__ u32 bw[2][256], sw[2][256];                    // 4 KB
    __shared__ u32 pnl[2][128];                               // 1 KB
    __shared__ float invl[64];
    __shared__ float sstat[4][64], cstat[4][64], estat[4][64];
    __shared__ float carr[64];
    __shared__ int sbase[256];

    int qb = blockIdx.x;                  // 0..63 (64-q slab)
    int el = blockIdx.y, e = e0 + el;
    int t = threadIdx.x;
    int q0 = qb * 64;
    int qw0 = qb * 2;

    bw[0][t] = pb[((size_t)e * QW + qw0) * B + t];
    bw[1][t] = pb[((size_t)e * QW + qw0 + 1) * B + t];
    sw[0][t] = ps[((size_t)e * QW + qw0) * B + t];
    sw[1][t] = ps[((size_t)e * QW + qw0 + 1) * B + t];
    if (t < 128) {
        pnl[0][t] = pn[((size_t)e * QW + qw0) * F + t];
        pnl[1][t] = pn[((size_t)e * QW + qw0 + 1) * F + t];
    } else if (t < 192) {
        invl[t - 128] = invn[(size_t)e * Q + q0 + (t - 128)];
    }
    __syncthreads();

    // ---- stage B fragments (1024 slots, 4/thread) ----
    #pragma unroll
    for (int s = 0; s < 4; s++) {
        int slot = t + 256 * s;
        int qg = slot >> 8;
        int r = slot & 255;
        int kb = r >> 6, lane2 = r & 63;
        int ql = qg * 16 + (lane2 & 15);
        int fb = kb * 32 + (lane2 >> 4) * 8;
        float iv = invl[ql];
        const u32* pw = pnl[ql >> 5];
        int sh = ql & 31;
        u16 tmp[8];
        #pragma unroll
        for (int j = 0; j < 8; j++) {
            u32 bit = (pw[fb + j] >> sh) & 1u;
            float v = bit ? 0.f : neg[(size_t)(fb + j) * Q + q0 + ql] * iv;
            tmp[j] = f2bf(v);
        }
        *(s8v*)&bfrag[qg][kb][lane2 * 8] = *(const s8v*)tmp;
    }
    __syncthreads();

    // ---- MFMA ----
    int wave = t >> 6, lane = t & 63;
    int colb = lane & 15, quad = lane >> 4;
    f32x4 acc[4][4];
    #pragma unroll
    for (int bgi = 0; bgi < 4; bgi++) {
        int bg = wave * 4 + bgi;
        s8v a[4];
        #pragma unroll
        for (int kb = 0; kb < 4; kb++)
            a[kb] = *(const s8v*)&af[((((size_t)e * 16 + bg) * 4 + kb) * 64 + lane) * 8];
        #pragma unroll
        for (int qg = 0; qg < 4; qg++) {
            f32x4 c4 = {0.f, 0.f, 0.f, 0.f};
            #pragma unroll
            for (int kb = 0; kb < 4; kb++) {
                s8v bv = *(const s8v*)&bfrag[qg][kb][lane * 8];
                c4 = __builtin_amdgcn_mfma_f32_16x16x32_bf16(a[kb], bv, c4, 0, 0, 0);
            }
            acc[bgi][qg] = c4;
        }
    }

    // ---- exp in place (M = 0 is safe: |sim*INV_TAU| <= ~5.2) ----
    #pragma unroll
    for (int bgi = 0; bgi < 4; bgi++)
        #pragma unroll
        for (int qg = 0; qg < 4; qg++)
            #pragma unroll
            for (int r = 0; r < 4; r++)
                acc[bgi][qg][r] = __expf(acc[bgi][qg][r]);

    // ---- column (boot) exp-sum + count ----
    float sloc[4] = {0.f, 0.f, 0.f, 0.f}, cloc[4] = {0.f, 0.f, 0.f, 0.f};
    #pragma unroll
    for (int bgi = 0; bgi < 4; bgi++) {
        int b0 = (wave * 4 + bgi) * 16 + quad * 4;
        uint4 w0 = *(const uint4*)&bw[0][b0];
        uint4 w1 = *(const uint4*)&bw[1][b0];
        u32 W0[4] = {w0.x, w0.y, w0.z, w0.w};
        u32 W1[4] = {w1.x, w1.y, w1.z, w1.w};
        #pragma unroll
        for (int r = 0; r < 4; r++)
            #pragma unroll
            for (int qg = 0; qg < 4; qg++) {
                u32 w = (qg & 2) ? W1[r] : W0[r];
                int bpos = (qg & 1) * 16 + colb;
                if ((w >> bpos) & 1u) {
                    sloc[qg] += acc[bgi][qg][r];
                    cloc[qg] += 1.f;
                }
            }
    }
    #pragma unroll
    for (int qg = 0; qg < 4; qg++) {
        sloc[qg] += __shfl_xor(sloc[qg], 16); sloc[qg] += __shfl_xor(sloc[qg], 32);
        cloc[qg] += __shfl_xor(cloc[qg], 16); cloc[qg] += __shfl_xor(cloc[qg], 32);
    }
    if (quad == 0)
        #pragma unroll
        for (int qg = 0; qg < 4; qg++) {
            sstat[wave][qg * 16 + colb] = sloc[qg];
            cstat[wave][qg * 16 + colb] = cloc[qg];
        }
    __syncthreads();
    float invS[4];
    #pragma unroll
    for (int qg = 0; qg < 4; qg++) {
        int c = qg * 16 + colb;
        float S = sstat[0][c] + sstat[1][c] + sstat[2][c] + sstat[3][c];
        invS[qg] = 1.f / fmaxf(S, 1e-30f);
    }
    if (wave == 0 && quad == 0)
        #pragma unroll
        for (int qg = 0; qg < 4; qg++) {
            int c = qg * 16 + colb;
            carr[c] = cstat[0][c] + cstat[1][c] + cstat[2][c] + cstat[3][c];
        }

    // ---- entropy (reuse exps) ----
    const float P0 = 1e-7f;
    const float C0 = 1.61180954e-6f;      // -P0*log(P0)
    float eloc[4] = {0.f, 0.f, 0.f, 0.f};
    #pragma unroll
    for (int bgi = 0; bgi < 4; bgi++) {
        int b0 = (wave * 4 + bgi) * 16 + quad * 4;
        uint4 w0 = *(const uint4*)&bw[0][b0];
        uint4 w1 = *(const uint4*)&bw[1][b0];
        u32 W0[4] = {w0.x, w0.y, w0.z, w0.w};
        u32 W1[4] = {w1.x, w1.y, w1.z, w1.w};
        #pragma unroll
        for (int r = 0; r < 4; r++)
            #pragma unroll
            for (int qg = 0; qg < 4; qg++) {
                u32 w = (qg & 2) ? W1[r] : W0[r];
                int bpos = (qg & 1) * 16 + colb;
                if ((w >> bpos) & 1u) {
                    float p = acc[bgi][qg][r] * invS[qg] + P0;
                    eloc[qg] -= p * __logf(p);
                } else {
                    eloc[qg] += C0;
                }
            }
    }
    #pragma unroll
    for (int qg = 0; qg < 4; qg++) {
        eloc[qg] += __shfl_xor(eloc[qg], 16); eloc[qg] += __shfl_xor(eloc[qg], 32);
    }
    if (quad == 0)
        #pragma unroll
        for (int qg = 0; qg < 4; qg++) estat[wave][qg * 16 + colb] = eloc[qg];

    // ---- per-row smask exp-sum partials -> rsum ----
    #pragma unroll
    for (int bgi = 0; bgi < 4; bgi++) {
        int b0 = (wave * 4 + bgi) * 16 + quad * 4;
        uint4 s0 = *(const uint4*)&sw[0][b0];
        uint4 s1 = *(const uint4*)&sw[1][b0];
        u32 S0[4] = {s0.x, s0.y, s0.z, s0.w};
        u32 S1[4] = {s1.x, s1.y, s1.z, s1.w};
        #pragma unroll
        for (int r = 0; r < 4; r++) {
            float rl = 0.f;
            #pragma unroll
            for (int qg = 0; qg < 4; qg++) {
                u32 w = (qg & 2) ? S1[r] : S0[r];
                int bpos = (qg & 1) * 16 + colb;
                if ((w >> bpos) & 1u) rl += acc[bgi][qg][r];
            }
            rl += __shfl_xor(rl, 1); rl += __shfl_xor(rl, 2);
            rl += __shfl_xor(rl, 4); rl += __shfl_xor(rl, 8);
            if (colb == 0 && rl != 0.f)
                atomicAdd(&rsum[el * B + b0 + r], rl);
        }
    }

    // ---- extraction reservation (per-b popc over both words) ----
    {
        u32 a0 = sw[0][t], a1 = sw[1][t];
        int n = __popc(a0) + __popc(a1);
        int base = 0;
        if (n) base = atomicAdd(&cnt_buf[el * B + t], n);
        sbase[t] = base;
    }
    __syncthreads();

    if (t < 64) {
        float tot = estat[0][t] + estat[1][t] + estat[2][t] + estat[3][t];
        atomicAdd(&unc[q0 + t], tot / fmaxf(carr[t], 1.f));
    }

    // ---- scatter compact (q, exp) entries ----
    #pragma unroll
    for (int bgi = 0; bgi < 4; bgi++) {
        int b0 = (wave * 4 + bgi) * 16 + quad * 4;
        uint4 s0 = *(const uint4*)&sw[0][b0];
        uint4 s1 = *(const uint4*)&sw[1][b0];
        u32 S0[4] = {s0.x, s0.y, s0.z, s0.w};
        u32 S1[4] = {s1.x, s1.y, s1.z, s1.w};
        #pragma unroll
        for (int r = 0; r < 4; r++) {
            int bs = sbase[b0 + r];
            int p0 = __popc(S0[r]);
            #pragma unroll
            for (int qg = 0; qg < 4; qg++) {
                int bpos = (qg & 1) * 16 + colb;
                u32 w = (qg & 2) ? S1[r] : S0[r];
                if ((w >> bpos) & 1u) {
                    int rank = __popc(w & ((1u << bpos) - 1u)) + ((qg & 2) ? p0 : 0);
                    int pos = bs + rank;
                    if (pos < CAP) {
                        uint2 en;
                        en.x = (unsigned)(q0 + qg * 16 + colb);
                        en.y = __builtin_bit_cast(unsigned, acc[bgi][qg][r]);
                        ent_buf[((size_t)(el * B + b0 + r)) * CAP + pos] = en;
                    }
                }
            }
        }
    }
}

// block per b (512 thr, 8 waves): pure scatter of precomputed probs into scores/cnt
__global__ void __launch_bounds__(512) k_scores(
        const uint2* __restrict__ ent_buf, const int* __restrict__ cnt_buf,
        const float* __restrict__ rsum,
        float* __restrict__ sacc, float* __restrict__ cacc, int ecnt) {
    __shared__ float srow[Q];
    __shared__ float crow[Q];
    __shared__ float isl[E];
    __shared__ int cl[E];
    int b = blockIdx.x, t = threadIdx.x;
    #pragma unroll
    for (int j = 0; j < 8; j++) { srow[t + 512 * j] = 0.f; crow[t + 512 * j] = 0.f; }
    if (t < ecnt) {
        int c = cnt_buf[t * B + b];
        cl[t] = (c > CAP) ? CAP : c;
        isl[t] = 1.f / fmaxf(rsum[t * B + b], 1e-30f);
    }
    __syncthreads();
    int wave = t >> 6, lane = t & 63;
    for (int el = wave; el < ecnt; el += 8) {
        int c = cl[el];
        float iS = isl[el];
        const uint2* p = ent_buf + (size_t)(el * B + b) * CAP;
        for (int i = lane; i < c; i += 64) {
            uint2 en = p[i];
            atomicAdd(&srow[en.x], __builtin_bit_cast(float, en.y) * iS);
            atomicAdd(&crow[en.x], 1.f);
        }
    }
    __syncthreads();
    #pragma unroll
    for (int j = 0; j < 8; j++) {
        int q = t + 512 * j;
        sacc[(size_t)b * Q + q] += srow[q];
        cacc[(size_t)b * Q + q] += crow[q];
    }
}

// block per b: full logits row + LSE stats from registers
__global__ void __launch_bounds__(256) k_logits(
        const float* __restrict__ query, const float* __restrict__ key,
        const float* __restrict__ neg, float* __restrict__ out,
        float* __restrict__ moco_part, float* __restrict__ nlse) {
    __shared__ float qrow[F];
    __shared__ float red[256];
    __shared__ float poss;
    int b = blockIdx.x, t = threadIdx.x;
    float pp = 0.f;
    if (t < F) { float qv = query[b * F + t]; qrow[t] = qv; pp = qv * key[b * F + t]; }
    red[t] = pp;
    __syncthreads();
    for (int s = 128; s > 0; s >>= 1) { if (t < s) red[t] += red[t + s]; __syncthreads(); }
    if (t == 0) poss = red[0] * INV_TAU;
    __syncthreads();
    float pos = poss;
    float4 acc[4];
    #pragma unroll
    for (int j = 0; j < 4; j++) acc[j] = make_float4(0.f, 0.f, 0.f, 0.f);
    for (int f = 0; f < F; f++) {
        float a = qrow[f];
        const float* np_ = neg + (size_t)f * Q + t * 4;
        #pragma unroll
        for (int j = 0; j < 4; j++) {
            float4 v = *(const float4*)&np_[1024 * j];
            acc[j].x = fmaf(a, v.x, acc[j].x);
            acc[j].y = fmaf(a, v.y, acc[j].y);
            acc[j].z = fmaf(a, v.z, acc[j].z);
            acc[j].w = fmaf(a, v.w, acc[j].w);
        }
    }
    float z[16];
    float* row = out + O_LOGITS + (size_t)b * (Q + 1);
    #pragma unroll
    for (int j = 0; j < 4; j++) {
        int q = t * 4 + 1024 * j;
        z[j * 4]     = acc[j].x * INV_TAU;
        z[j * 4 + 1] = acc[j].y * INV_TAU;
        z[j * 4 + 2] = acc[j].z * INV_TAU;
        z[j * 4 + 3] = acc[j].w * INV_TAU;
        row[1 + q]     = z[j * 4];
        row[1 + q + 1] = z[j * 4 + 1];
        row[1 + q + 2] = z[j * 4 + 2];
        row[1 + q + 3] = z[j * 4 + 3];
    }
    if (t == 0) row[0] = pos;
    // neg-only max
    float mn = -INFINITY;
    #pragma unroll
    for (int j = 0; j < 16; j++) mn = fmaxf(mn, z[j]);
    red[t] = mn; __syncthreads();
    for (int s = 128; s > 0; s >>= 1) { if (t < s) red[t] = fmaxf(red[t], red[t + s]); __syncthreads(); }
    float Mn = red[0];
    float M = fmaxf(Mn, pos);             // full-row max
    __syncthreads();
    float s2 = 0.f;
    #pragma unroll
    for (int j = 0; j < 16; j++) s2 += expf(z[j] - Mn);
    red[t] = s2; __syncthreads();
    for (int s = 128; s > 0; s >>= 1) { if (t < s) red[t] += red[t + s]; __syncthreads(); }
    float Sn = red[0]; __syncthreads();
    float s1 = 0.f;
    #pragma unroll
    for (int j = 0; j < 16; j++) s1 += expf(z[j] - M);
    if (t == 0) s1 += expf(pos - M);
    red[t] = s1; __syncthreads();
    for (int s = 128; s > 0; s >>= 1) { if (t < s) red[t] += red[t + s]; __syncthreads(); }
    if (t == 0) {
        moco_part[b] = M + logf(red[0]) - pos;
        nlse[b] = Mn + logf(Sn);
    }
}

// normalize unc (/E), bitonic sort 4096, median per np.quantile 'linear'
__global__ void k_median(float* __restrict__ unc, float* __restrict__ ubp) {
    __shared__ float sd[4096];
    int t = threadIdx.x;
    #pragma unroll
    for (int j = 0; j < 4; j++) {
        int q = t + 1024 * j;
        float u = unc[q] * (1.f / 128.f);
        unc[q] = u; sd[q] = u;
    }
    __syncthreads();
    for (int k = 2; k <= 4096; k <<= 1) {
        for (int j = k >> 1; j > 0; j >>= 1) {
            #pragma unroll
            for (int base = 0; base < 4; base++) {
                int i = t + 1024 * base;
                int ixj = i ^ j;
                if (ixj > i) {
                    bool up = ((i & k) == 0);
                    float x = sd[i], y = sd[ixj];
                    if ((x > y) == up) { sd[i] = y; sd[ixj] = x; }
                }
            }
            __syncthreads();
        }
    }
    if (t == 0) { float a = sd[2047], b2 = sd[2048]; ubp[0] = a + 0.5f * (b2 - a); }
}

// per (b, mode): argmax of scores (=sacc/max(cacc,1)) among allowed q, mask + loss
__global__ void k_select(float* __restrict__ out, const float* __restrict__ sacc,
                         const float* __restrict__ cacc,
                         const float* __restrict__ unc, const float* __restrict__ ubp,
                         const float* __restrict__ nlse, float* __restrict__ easy_part,
                         float* __restrict__ hard_part) {
    __shared__ float rv[256];
    __shared__ int ri[256];
    __shared__ int bshare;
    int b = blockIdx.x, mode = blockIdx.y, t = threadIdx.x;
    float ub = ubp[0];
    float bv = -INFINITY; int bidx = Q;
    #pragma unroll
    for (int j = 0; j < 16; j++) {
        int q = t + 256 * j;
        float u = unc[q];
        bool ok = (mode == 0) ? (u <= ub) : (u >= ub);
        if (ok) {
            float v = sacc[(size_t)b * Q + q] / fmaxf(cacc[(size_t)b * Q + q], 1.f);
            if (v > bv || (v == bv && q < bidx)) { bv = v; bidx = q; }
        }
    }
    rv[t] = bv; ri[t] = bidx; __syncthreads();
    for (int s = 128; s > 0; s >>= 1) {
        if (t < s) {
            float v2 = rv[t + s]; int i2 = ri[t + s];
            if (v2 > rv[t] || (v2 == rv[t] && i2 < ri[t])) { rv[t] = v2; ri[t] = i2; }
        }
        __syncthreads();
    }
    if (t == 0) {
        int best = ri[0]; bshare = best;
        float zz = out[O_LOGITS + (size_t)b * (Q + 1) + 1 + best];
        float loss = nlse[b] - zz;
        (mode == 0 ? easy_part : hard_part)[b] = loss;
    }
    __syncthreads();
    int best = bshare;
    float* mrow = out + (mode == 0 ? O_EMASK : O_HMASK) + (size_t)b * Q;
    #pragma unroll
    for (int j = 0; j < 16; j++) { int q = t + 256 * j; mrow[q] = (q == best) ? 1.f : 0.f; }
}

__global__ void k_scalars(const float* __restrict__ moco, const float* __restrict__ easyp,
                          const float* __restrict__ hardp, float* __restrict__ out) {
    __shared__ float red[256];
    int t = threadIdx.x;
    red[t] = moco[t]; __syncthreads();
    for (int s = 128; s > 0; s >>= 1) { if (t < s) red[t] += red[t + s]; __syncthreads(); }
    if (t == 0) out[O_MOCO] = red[0] / 256.f;
    __syncthreads();
    red[t] = easyp[t]; __syncthreads();
    for (int s = 128; s > 0; s >>= 1) { if (t < s) red[t] += red[t + s]; __syncthreads(); }
    if (t == 0) out[O_ELOSS] = red[0] / 256.f;
    __syncthreads();
    red[t] = hardp[t]; __syncthreads();
    for (int s = 128; s > 0; s >>= 1) { if (t < s) red[t] += red[t + s]; __syncthreads(); }
    if (t == 0) out[O_HLOSS] = red[0] / 256.f;
}

extern "C" void kernel_launch(void* const* d_in, const int* in_sizes, int n_in,
                              void* d_out, int out_size, void* d_ws, size_t ws_size,
                              hipStream_t stream) {
    const float* query   = (const float*)d_in[0];
    const float* key     = (const float*)d_in[1];
    const float* teacher = (const float*)d_in[2];
    const float* neg     = (const float*)d_in[3];
    const u8* mask_t     = (const u8*)d_in[4];
    const u8* mask_n     = (const u8*)d_in[5];
    const u8* score_mask = (const u8*)d_in[6];
    const u8* boot_mask  = (const u8*)d_in[7];
    float* out = (float*)d_out;
    float* ws  = (float*)d_ws;

    long ws_floats = (long)(ws_size / 4);
    int Ec = (int)((ws_floats - (long)W_ENT) / (long)(B * CAP * 2));
    if (Ec > E) Ec = E;
    if (Ec < 1) Ec = 1;

    u16* af = (u16*)(ws + W_AF);
    u32* pb = (u32*)(ws + W_PB);
    u32* ps = (u32*)(ws + W_PS);
    u32* pn = (u32*)(ws + W_PN);
    int* cnt_buf = (int*)(ws + W_CNTB);
    float* rsum = ws + W_RSUM;
    uint2* ent_buf = (uint2*)(ws + W_ENT);

    // zero scores + cnt + unc + cnt_buf + rsum (contiguous 2166784 floats)
    k_zero<<<NZERO / 1024, 256, 0, stream>>>((float4*)(ws + W_SCORES));
    k_pack<<<dim3((E * B) / 64, Q / 512, 3), 256, 0, stream>>>(
        boot_mask, score_mask, mask_n, pb, ps, pn);
    k_afrag<<<E * B, 128, 0, stream>>>(teacher, mask_t, af);
    k_invn<<<dim3(E, 4), 256, 0, stream>>>(neg, pn, ws + W_INVN);
    k_logits<<<B, 256, 0, stream>>>(query, key, neg, out, ws + W_MOCO, ws + W_NLSE);

    for (int e0 = 0; e0 < E; e0 += Ec) {
        int ecnt = (E - e0 < Ec) ? (E - e0) : Ec;
        if (e0 > 0)
            k_zero<<<64, 256, 0, stream>>>((float4*)(ws + W_CNTB));  // cnt_buf+rsum
        k_fused<<<dim3(Q / 64, ecnt), 256, 0, stream>>>(
            af, neg, pn, ws + W_INVN, pb, ps, ws + W_UNC, ent_buf, cnt_buf, rsum, e0);
        k_scores<<<B, 512, 0, stream>>>(ent_buf, cnt_buf, rsum,
                                        ws + W_SCORES, ws + W_CNT, ecnt);
    }

    k_median<<<1, 1024, 0, stream>>>(ws + W_UNC, ws + W_UB);
    k_select<<<dim3(B, 2), 256, 0, stream>>>(out, ws + W_SCORES, ws + W_CNT,
                                             ws + W_UNC, ws + W_UB,
                                             ws + W_NLSE, ws + W_EASY, ws + W_HARD);
    k_scalars<<<1, 256, 0, stream>>>(ws + W_MOCO, ws + W_EASY, ws + W_HARD, out);
}

// Round 8
// 1477.287 us; speedup vs baseline: 1.0162x; 1.0162x over previous
//
#include <hip/hip_runtime.h>
#include <cmath>

typedef unsigned char u8;
typedef unsigned short u16;
typedef unsigned int u32;
typedef __attribute__((ext_vector_type(8))) short s8v;    // 8 bf16 = 4 VGPRs
typedef __attribute__((ext_vector_type(4))) float f32x4;  // MFMA acc

#define B 256
#define F 128
#define Q 4096
#define E 128
#define QW 128               // Q/32 words per row
#define INV_TAU 5.0f
#define CAP 256              // compact entries per (e,b); binomial(4096,1/32) max ~180

// ---- ws layout (offsets in floats) ----
#define W_SCORES 0u            // B*Q = 1048576
#define W_CNT    1048576u      // B*Q
#define W_UNC    2097152u      // 4096
#define W_CNTB   2101248u      // E*B ints = 32768
#define W_NLSE   2134016u      // 256
#define W_MOCO   2134272u
#define W_EASY   2134528u
#define W_HARD   2134784u
#define W_UB     2135040u      // 256 pad
#define W_INVN   2135296u      // E*Q = 524288
#define W_AF     2659584u      // bf16 E*B*F -> 2097152 floats
#define W_PB     4756736u      // packed boot  E*QW*B words = 4194304
#define W_PS     8951040u      // packed smask E*QW*B words = 4194304
#define W_PN     13145344u     // packed mask_n E*QW*F words = 2097152
#define W_ENT    15242496u     // Ec*256*CAP uint2 -> Ec*131072 floats
#define NZERO    2134016u      // zero range: SCORES..CNTB end (2084*1024)

// ---- out layout (floats) ----
#define O_MOCO   0u
#define O_LOGITS 1u            // (B, Q+1)
#define O_ELOSS  1048833u
#define O_EMASK  1048834u      // (B, Q)
#define O_HLOSS  2097410u
#define O_HMASK  2097411u      // (B, Q)

static __device__ __forceinline__ u16 f2bf(float x) {
    unsigned int u = __builtin_bit_cast(unsigned int, x);
    unsigned int r = (u + 0x7FFFu + ((u >> 16) & 1u)) >> 16;
    return (u16)r;
}

__global__ void k_zero(float4* __restrict__ p) {
    p[(size_t)blockIdx.x * 256 + threadIdx.x] = make_float4(0.f, 0.f, 0.f, 0.f);
}

// ---- bit-pack all three masks; z selects tensor. out[e][qw][r] transposed words.
__global__ void __launch_bounds__(256) k_pack(const u8* __restrict__ boot,
                                              const u8* __restrict__ smask,
                                              const u8* __restrict__ maskn,
                                              u32* __restrict__ pb, u32* __restrict__ ps,
                                              u32* __restrict__ pn) {
    int z = blockIdx.z;
    int Rin = (z == 2) ? F : B;
    if (z == 2 && blockIdx.x >= 2048) return;
    const u8* in = (z == 0) ? boot : (z == 1) ? smask : maskn;
    u32* out = (z == 0) ? pb : (z == 1) ? ps : pn;
    __shared__ u32 lds[64 * 133];
    int t = threadIdx.x;
    int r0 = blockIdx.x * 64;
    int q0 = blockIdx.y * 512;
    int qw0 = q0 >> 5;
    #pragma unroll
    for (int i = 0; i < 8; i++) {
        int w = i * 256 + t;
        int row = w >> 5, c = w & 31;
        uint4 v = *(const uint4*)&in[(size_t)(r0 + row) * Q + q0 + c * 16];
        int base = row * 133 + c * 4;
        lds[base] = v.x; lds[base + 1] = v.y; lds[base + 2] = v.z; lds[base + 3] = v.w;
    }
    __syncthreads();
    int e = r0 / Rin, rr = r0 % Rin;
    #pragma unroll
    for (int k = 0; k < 4; k++) {
        int qw = (t >> 6) + k * 4;
        int r = t & 63;
        u32 w = 0;
        #pragma unroll
        for (int j = 0; j < 8; j++) {
            u32 u = lds[r * 133 + qw * 8 + j];
            w |= ((u & 1u) | ((u >> 7) & 2u) | ((u >> 14) & 4u) | ((u >> 21) & 8u)) << (j * 4);
        }
        out[((size_t)e * QW + qw0 + qw) * Rin + rr + r] = w;
    }
}

// one block (128 thr) per (e,b): masked l2-norm of teacher row -> bf16 A-fragments
__global__ void k_afrag(const float* __restrict__ teacher, const u8* __restrict__ mask_t,
                        u16* __restrict__ af) {
    int eb = blockIdx.x;
    int e  = eb >> 8;
    int b  = eb & (B - 1);
    int f  = threadIdx.x;
    float v = mask_t[(size_t)eb * F + f] ? 0.f : teacher[b * F + f];
    float ss = v * v;
    #pragma unroll
    for (int o = 32; o > 0; o >>= 1) ss += __shfl_down(ss, o);
    __shared__ float s2[2];
    if ((threadIdx.x & 63) == 0) s2[threadIdx.x >> 6] = ss;
    __syncthreads();
    float d = fmaxf(sqrtf(s2[0] + s2[1]), 1e-12f);
    float t = v / d;
    int bg = b >> 4, m = b & 15;
    int kb = f >> 5, quad = (f >> 3) & 3, j = f & 7;
    int lane = quad * 16 + m;
    af[((((size_t)e * 16 + bg) * 4 + kb) * 64 + lane) * 8 + j] = f2bf(t);
}

// per (e, 1024-q block): 1/(TAU*||masked neg col||)
__global__ void __launch_bounds__(256) k_invn(const float* __restrict__ neg,
                                              const u32* __restrict__ pn,
                                              float* __restrict__ invn) {
    __shared__ u32 lds[32 * 128];
    int e = blockIdx.x, t = threadIdx.x;
    int qblk = blockIdx.y;
    size_t base = ((size_t)e * QW + qblk * 32) * F;
    #pragma unroll
    for (int k = 0; k < 16; k++) lds[t + 256 * k] = pn[base + t + 256 * k];
    __syncthreads();
    int q0 = qblk * 1024 + t * 4;
    int qwl = (t * 4) >> 5;
    int sh = (t * 4) & 31;
    float s0 = 0.f, s1 = 0.f, s2 = 0.f, s3 = 0.f;
    #pragma unroll 4
    for (int f = 0; f < F; f++) {
        float4 v = *(const float4*)&neg[(size_t)f * Q + q0];
        u32 w = lds[qwl * 128 + f] >> sh;
        if (!(w & 1u)) s0 = fmaf(v.x, v.x, s0);
        if (!(w & 2u)) s1 = fmaf(v.y, v.y, s1);
        if (!(w & 4u)) s2 = fmaf(v.z, v.z, s2);
        if (!(w & 8u)) s3 = fmaf(v.w, v.w, s3);
    }
    float4 r;
    r.x = INV_TAU / fmaxf(sqrtf(s0), 1e-12f);
    r.y = INV_TAU / fmaxf(sqrtf(s1), 1e-12f);
    r.z = INV_TAU / fmaxf(sqrtf(s2), 1e-12f);
    r.w = INV_TAU / fmaxf(sqrtf(s3), 1e-12f);
    *(float4*)&invn[(size_t)e * Q + q0] = r;
}

// Fused: per (e, 64-q slab): B-frags inline, MFMA, exp in place, column softmax+
// entropy (boot), popc-reserved extraction of (q, exp) smask entries.
__global__ void __launch_bounds__(256) k_fused(
        const u16* __restrict__ af, const float* __restrict__ neg,
        const u32* __restrict__ pn, const float* __restrict__ invn,
        const u32* __restrict__ pb, const u32* __restrict__ ps,
        float* __restrict__ unc, uint2* __restrict__ ent_buf,
        int* __restrict__ cnt_buf, int e0) {
    __shared__ u16 bfrag[4][4][512];                          // 16 KB
    __shared__ u32 bw[2][256], sw[2][256];                    // 4 KB
    __shared__ u32 pnl[2][128];                               // 1 KB
    __shared__ float invl[64];
    __shared__ float sstat[4][64], cstat[4][64], estat[4][64];
    __shared__ float carr[64];
    __shared__ int sbase[256];

    int qb = blockIdx.x;                  // 0..63 (64-q slab)
    int el = blockIdx.y, e = e0 + el;
    int t = threadIdx.x;
    int q0 = qb * 64;
    int qw0 = qb * 2;

    bw[0][t] = pb[((size_t)e * QW + qw0) * B + t];
    bw[1][t] = pb[((size_t)e * QW + qw0 + 1) * B + t];
    sw[0][t] = ps[((size_t)e * QW + qw0) * B + t];
    sw[1][t] = ps[((size_t)e * QW + qw0 + 1) * B + t];
    if (t < 128) {
        pnl[0][t] = pn[((size_t)e * QW + qw0) * F + t];
        pnl[1][t] = pn[((size_t)e * QW + qw0 + 1) * F + t];
    } else if (t < 192) {
        invl[t - 128] = invn[(size_t)e * Q + q0 + (t - 128)];
    }
    __syncthreads();

    // ---- stage B fragments (1024 slots, 4/thread) ----
    #pragma unroll
    for (int s = 0; s < 4; s++) {
        int slot = t + 256 * s;
        int qg = slot >> 8;
        int r = slot & 255;
        int kb = r >> 6, lane2 = r & 63;
        int ql = qg * 16 + (lane2 & 15);
        int fb = kb * 32 + (lane2 >> 4) * 8;
        float iv = invl[ql];
        const u32* pw = pnl[ql >> 5];
        int sh = ql & 31;
        u16 tmp[8];
        #pragma unroll
        for (int j = 0; j < 8; j++) {
            u32 bit = (pw[fb + j] >> sh) & 1u;
            float v = bit ? 0.f : neg[(size_t)(fb + j) * Q + q0 + ql] * iv;
            tmp[j] = f2bf(v);
        }
        *(s8v*)&bfrag[qg][kb][lane2 * 8] = *(const s8v*)tmp;
    }
    __syncthreads();

    // ---- MFMA ----
    int wave = t >> 6, lane = t & 63;
    int colb = lane & 15, quad = lane >> 4;
    f32x4 acc[4][4];
    #pragma unroll
    for (int bgi = 0; bgi < 4; bgi++) {
        int bg = wave * 4 + bgi;
        s8v a[4];
        #pragma unroll
        for (int kb = 0; kb < 4; kb++)
            a[kb] = *(const s8v*)&af[((((size_t)e * 16 + bg) * 4 + kb) * 64 + lane) * 8];
        #pragma unroll
        for (int qg = 0; qg < 4; qg++) {
            f32x4 c4 = {0.f, 0.f, 0.f, 0.f};
            #pragma unroll
            for (int kb = 0; kb < 4; kb++) {
                s8v bv = *(const s8v*)&bfrag[qg][kb][lane * 8];
                c4 = __builtin_amdgcn_mfma_f32_16x16x32_bf16(a[kb], bv, c4, 0, 0, 0);
            }
            acc[bgi][qg] = c4;
        }
    }

    // ---- exp in place (M = 0 is safe: |sim*INV_TAU| <= ~5.2) ----
    #pragma unroll
    for (int bgi = 0; bgi < 4; bgi++)
        #pragma unroll
        for (int qg = 0; qg < 4; qg++)
            #pragma unroll
            for (int r = 0; r < 4; r++)
                acc[bgi][qg][r] = __expf(acc[bgi][qg][r]);

    // ---- column (boot) exp-sum + count ----
    float sloc[4] = {0.f, 0.f, 0.f, 0.f}, cloc[4] = {0.f, 0.f, 0.f, 0.f};
    #pragma unroll
    for (int bgi = 0; bgi < 4; bgi++) {
        int b0 = (wave * 4 + bgi) * 16 + quad * 4;
        uint4 w0 = *(const uint4*)&bw[0][b0];
        uint4 w1 = *(const uint4*)&bw[1][b0];
        u32 W0[4] = {w0.x, w0.y, w0.z, w0.w};
        u32 W1[4] = {w1.x, w1.y, w1.z, w1.w};
        #pragma unroll
        for (int r = 0; r < 4; r++)
            #pragma unroll
            for (int qg = 0; qg < 4; qg++) {
                u32 w = (qg & 2) ? W1[r] : W0[r];
                int bpos = (qg & 1) * 16 + colb;
                if ((w >> bpos) & 1u) {
                    sloc[qg] += acc[bgi][qg][r];
                    cloc[qg] += 1.f;
                }
            }
    }
    #pragma unroll
    for (int qg = 0; qg < 4; qg++) {
        sloc[qg] += __shfl_xor(sloc[qg], 16); sloc[qg] += __shfl_xor(sloc[qg], 32);
        cloc[qg] += __shfl_xor(cloc[qg], 16); cloc[qg] += __shfl_xor(cloc[qg], 32);
    }
    if (quad == 0)
        #pragma unroll
        for (int qg = 0; qg < 4; qg++) {
            sstat[wave][qg * 16 + colb] = sloc[qg];
            cstat[wave][qg * 16 + colb] = cloc[qg];
        }
    __syncthreads();
    float invS[4];
    #pragma unroll
    for (int qg = 0; qg < 4; qg++) {
        int c = qg * 16 + colb;
        float S = sstat[0][c] + sstat[1][c] + sstat[2][c] + sstat[3][c];
        invS[qg] = 1.f / fmaxf(S, 1e-30f);
    }
    if (wave == 0 && quad == 0)
        #pragma unroll
        for (int qg = 0; qg < 4; qg++) {
            int c = qg * 16 + colb;
            carr[c] = cstat[0][c] + cstat[1][c] + cstat[2][c] + cstat[3][c];
        }

    // ---- entropy (reuse exps) ----
    const float P0 = 1e-7f;
    const float C0 = 1.61180954e-6f;      // -P0*log(P0)
    float eloc[4] = {0.f, 0.f, 0.f, 0.f};
    #pragma unroll
    for (int bgi = 0; bgi < 4; bgi++) {
        int b0 = (wave * 4 + bgi) * 16 + quad * 4;
        uint4 w0 = *(const uint4*)&bw[0][b0];
        uint4 w1 = *(const uint4*)&bw[1][b0];
        u32 W0[4] = {w0.x, w0.y, w0.z, w0.w};
        u32 W1[4] = {w1.x, w1.y, w1.z, w1.w};
        #pragma unroll
        for (int r = 0; r < 4; r++)
            #pragma unroll
            for (int qg = 0; qg < 4; qg++) {
                u32 w = (qg & 2) ? W1[r] : W0[r];
                int bpos = (qg & 1) * 16 + colb;
                if ((w >> bpos) & 1u) {
                    float p = acc[bgi][qg][r] * invS[qg] + P0;
                    eloc[qg] -= p * __logf(p);
                } else {
                    eloc[qg] += C0;
                }
            }
    }
    #pragma unroll
    for (int qg = 0; qg < 4; qg++) {
        eloc[qg] += __shfl_xor(eloc[qg], 16); eloc[qg] += __shfl_xor(eloc[qg], 32);
    }
    if (quad == 0)
        #pragma unroll
        for (int qg = 0; qg < 4; qg++) estat[wave][qg * 16 + colb] = eloc[qg];

    // ---- extraction reservation (per-b popc over both words) ----
    {
        u32 a0 = sw[0][t], a1 = sw[1][t];
        int n = __popc(a0) + __popc(a1);
        int base = 0;
        if (n) base = atomicAdd(&cnt_buf[el * B + t], n);
        sbase[t] = base;
    }
    __syncthreads();

    if (t < 64) {
        float tot = estat[0][t] + estat[1][t] + estat[2][t] + estat[3][t];
        atomicAdd(&unc[q0 + t], tot / fmaxf(carr[t], 1.f));
    }

    // ---- scatter compact (q, exp) entries; word-level early-out (3% density) ----
    u32 cmask = 0x00010001u << colb;
    #pragma unroll
    for (int bgi = 0; bgi < 4; bgi++) {
        int b0 = (wave * 4 + bgi) * 16 + quad * 4;
        uint4 s0 = *(const uint4*)&sw[0][b0];
        uint4 s1 = *(const uint4*)&sw[1][b0];
        u32 S0[4] = {s0.x, s0.y, s0.z, s0.w};
        u32 S1[4] = {s1.x, s1.y, s1.z, s1.w};
        #pragma unroll
        for (int r = 0; r < 4; r++) {
            if (!((S0[r] | S1[r]) & cmask)) continue;
            int bs = sbase[b0 + r];
            int p0 = __popc(S0[r]);
            #pragma unroll
            for (int qg = 0; qg < 4; qg++) {
                int bpos = (qg & 1) * 16 + colb;
                u32 w = (qg & 2) ? S1[r] : S0[r];
                if ((w >> bpos) & 1u) {
                    int rank = __popc(w & ((1u << bpos) - 1u)) + ((qg & 2) ? p0 : 0);
                    int pos = bs + rank;
                    if (pos < CAP) {
                        uint2 en;
                        en.x = (unsigned)(q0 + qg * 16 + colb);
                        en.y = __builtin_bit_cast(unsigned, acc[bgi][qg][r]);
                        ent_buf[((size_t)(el * B + b0 + r)) * CAP + pos] = en;
                    }
                }
            }
        }
    }
}

// block per b (512 thr): sum entry-exps per el (row denom) then scatter probs
__global__ void __launch_bounds__(512) k_scores(
        const uint2* __restrict__ ent_buf, const int* __restrict__ cnt_buf,
        float* __restrict__ sacc, float* __restrict__ cacc, int ecnt) {
    __shared__ float srow[Q];
    __shared__ float crow[Q];
    __shared__ int cl[E];
    int b = blockIdx.x, t = threadIdx.x;
    #pragma unroll
    for (int j = 0; j < 8; j++) { srow[t + 512 * j] = 0.f; crow[t + 512 * j] = 0.f; }
    if (t < ecnt) {
        int c = cnt_buf[t * B + b];
        cl[t] = (c > CAP) ? CAP : c;
    }
    __syncthreads();
    int wave = t >> 6, lane = t & 63;
    for (int el = wave; el < ecnt; el += 8) {
        int c = cl[el];
        if (c == 0) continue;
        const uint2* p = ent_buf + (size_t)(el * B + b) * CAP;
        uint2 ev[4]; int ne = 0;
        float s = 0.f;
        for (int i = lane; i < c; i += 64) {
            ev[ne] = p[i];
            s += __builtin_bit_cast(float, ev[ne].y);
            ne++;
        }
        #pragma unroll
        for (int off = 32; off > 0; off >>= 1) s += __shfl_xor(s, off);
        float iS = 1.f / fmaxf(s, 1e-30f);
        for (int k = 0; k < ne; k++) {
            atomicAdd(&srow[ev[k].x], __builtin_bit_cast(float, ev[k].y) * iS);
            atomicAdd(&crow[ev[k].x], 1.f);
        }
    }
    __syncthreads();
    #pragma unroll
    for (int j = 0; j < 8; j++) {
        int q = t + 512 * j;
        sacc[(size_t)b * Q + q] += srow[q];
        cacc[(size_t)b * Q + q] += crow[q];
    }
}

// (b, seg) grid: logits slab of 1024 q; seg 0 also writes pos logit
__global__ void k_logits(const float* __restrict__ query, const float* __restrict__ key,
                         const float* __restrict__ neg, float* __restrict__ out) {
    __shared__ float qrow[F];
    __shared__ float red[256];
    int b = blockIdx.x, seg = blockIdx.y, t = threadIdx.x;
    if (t < F) qrow[t] = query[b * F + t];
    __syncthreads();
    int q0 = seg * 1024 + t * 4;
    float4 acc = make_float4(0.f, 0.f, 0.f, 0.f);
    for (int f = 0; f < F; f++) {
        float a = qrow[f];
        float4 v = *(const float4*)&neg[(size_t)f * Q + q0];
        acc.x = fmaf(a, v.x, acc.x);
        acc.y = fmaf(a, v.y, acc.y);
        acc.z = fmaf(a, v.z, acc.z);
        acc.w = fmaf(a, v.w, acc.w);
    }
    float* row = out + O_LOGITS + (size_t)b * (Q + 1);
    row[1 + q0]     = acc.x * INV_TAU;
    row[1 + q0 + 1] = acc.y * INV_TAU;
    row[1 + q0 + 2] = acc.z * INV_TAU;
    row[1 + q0 + 3] = acc.w * INV_TAU;
    if (seg == 0) {
        float pp = (t < F) ? qrow[t] * key[b * F + t] : 0.f;
        red[t] = pp;
        __syncthreads();
        for (int s = 128; s > 0; s >>= 1) { if (t < s) red[t] += red[t + s]; __syncthreads(); }
        if (t == 0) row[0] = red[0] * INV_TAU;
    }
}

// block per b: moco part (full-row LSE - z0) and neg-only LSE
__global__ void k_rowstats(const float* __restrict__ out, float* __restrict__ moco_part,
                           float* __restrict__ nlse) {
    __shared__ float red[256];
    int b = blockIdx.x, t = threadIdx.x;
    const float* row = out + O_LOGITS + (size_t)b * (Q + 1);
    float m = -INFINITY, mn = -INFINITY;
    for (int j = 0; j < 17; j++) {
        int i = t + 256 * j;
        if (i < Q + 1) { float zz = row[i]; m = fmaxf(m, zz); if (i >= 1) mn = fmaxf(mn, zz); }
    }
    red[t] = m; __syncthreads();
    for (int s = 128; s > 0; s >>= 1) { if (t < s) red[t] = fmaxf(red[t], red[t + s]); __syncthreads(); }
    float M = red[0]; __syncthreads();
    red[t] = mn; __syncthreads();
    for (int s = 128; s > 0; s >>= 1) { if (t < s) red[t] = fmaxf(red[t], red[t + s]); __syncthreads(); }
    float Mn = red[0]; __syncthreads();
    float s1 = 0.f, s2 = 0.f;
    for (int j = 0; j < 17; j++) {
        int i = t + 256 * j;
        if (i < Q + 1) { float zz = row[i]; s1 += expf(zz - M); if (i >= 1) s2 += expf(zz - Mn); }
    }
    red[t] = s1; __syncthreads();
    for (int s = 128; s > 0; s >>= 1) { if (t < s) red[t] += red[t + s]; __syncthreads(); }
    float S = red[0]; __syncthreads();
    red[t] = s2; __syncthreads();
    for (int s = 128; s > 0; s >>= 1) { if (t < s) red[t] += red[t + s]; __syncthreads(); }
    float Sn = red[0];
    if (t == 0) { moco_part[b] = M + logf(S) - row[0]; nlse[b] = Mn + logf(Sn); }
}

// normalize unc (/E), bitonic sort 4096, median per np.quantile 'linear'
__global__ void k_median(float* __restrict__ unc, float* __restrict__ ubp) {
    __shared__ float sd[4096];
    int t = threadIdx.x;
    #pragma unroll
    for (int j = 0; j < 4; j++) {
        int q = t + 1024 * j;
        float u = unc[q] * (1.f / 128.f);
        unc[q] = u; sd[q] = u;
    }
    __syncthreads();
    for (int k = 2; k <= 4096; k <<= 1) {
        for (int j = k >> 1; j > 0; j >>= 1) {
            #pragma unroll
            for (int base = 0; base < 4; base++) {
                int i = t + 1024 * base;
                int ixj = i ^ j;
                if (ixj > i) {
                    bool up = ((i & k) == 0);
                    float x = sd[i], y = sd[ixj];
                    if ((x > y) == up) { sd[i] = y; sd[ixj] = x; }
                }
            }
            __syncthreads();
        }
    }
    if (t == 0) { float a = sd[2047], b2 = sd[2048]; ubp[0] = a + 0.5f * (b2 - a); }
}

// per (b, mode): argmax of scores (=sacc/max(cacc,1)) among allowed q, mask + loss
__global__ void k_select(float* __restrict__ out, const float* __restrict__ sacc,
                         const float* __restrict__ cacc,
                         const float* __restrict__ unc, const float* __restrict__ ubp,
                         const float* __restrict__ nlse, float* __restrict__ easy_part,
                         float* __restrict__ hard_part) {
    __shared__ float rv[256];
    __shared__ int ri[256];
    __shared__ int bshare;
    int b = blockIdx.x, mode = blockIdx.y, t = threadIdx.x;
    float ub = ubp[0];
    float bv = -INFINITY; int bidx = Q;
    #pragma unroll
    for (int j = 0; j < 16; j++) {
        int q = t + 256 * j;
        float u = unc[q];
        bool ok = (mode == 0) ? (u <= ub) : (u >= ub);
        if (ok) {
            float v = sacc[(size_t)b * Q + q] / fmaxf(cacc[(size_t)b * Q + q], 1.f);
            if (v > bv || (v == bv && q < bidx)) { bv = v; bidx = q; }
        }
    }
    rv[t] = bv; ri[t] = bidx; __syncthreads();
    for (int s = 128; s > 0; s >>= 1) {
        if (t < s) {
            float v2 = rv[t + s]; int i2 = ri[t + s];
            if (v2 > rv[t] || (v2 == rv[t] && i2 < ri[t])) { rv[t] = v2; ri[t] = i2; }
        }
        __syncthreads();
    }
    if (t == 0) {
        int best = ri[0]; bshare = best;
        float zz = out[O_LOGITS + (size_t)b * (Q + 1) + 1 + best];
        float loss = nlse[b] - zz;
        (mode == 0 ? easy_part : hard_part)[b] = loss;
    }
    __syncthreads();
    int best = bshare;
    float* mrow = out + (mode == 0 ? O_EMASK : O_HMASK) + (size_t)b * Q;
    #pragma unroll
    for (int j = 0; j < 16; j++) { int q = t + 256 * j; mrow[q] = (q == best) ? 1.f : 0.f; }
}

__global__ void k_scalars(const float* __restrict__ moco, const float* __restrict__ easyp,
                          const float* __restrict__ hardp, float* __restrict__ out) {
    __shared__ float red[256];
    int t = threadIdx.x;
    red[t] = moco[t]; __syncthreads();
    for (int s = 128; s > 0; s >>= 1) { if (t < s) red[t] += red[t + s]; __syncthreads(); }
    if (t == 0) out[O_MOCO] = red[0] / 256.f;
    __syncthreads();
    red[t] = easyp[t]; __syncthreads();
    for (int s = 128; s > 0; s >>= 1) { if (t < s) red[t] += red[t + s]; __syncthreads(); }
    if (t == 0) out[O_ELOSS] = red[0] / 256.f;
    __syncthreads();
    red[t] = hardp[t]; __syncthreads();
    for (int s = 128; s > 0; s >>= 1) { if (t < s) red[t] += red[t + s]; __syncthreads(); }
    if (t == 0) out[O_HLOSS] = red[0] / 256.f;
}

extern "C" void kernel_launch(void* const* d_in, const int* in_sizes, int n_in,
                              void* d_out, int out_size, void* d_ws, size_t ws_size,
                              hipStream_t stream) {
    const float* query   = (const float*)d_in[0];
    const float* key     = (const float*)d_in[1];
    const float* teacher = (const float*)d_in[2];
    const float* neg     = (const float*)d_in[3];
    const u8* mask_t     = (const u8*)d_in[4];
    const u8* mask_n     = (const u8*)d_in[5];
    const u8* score_mask = (const u8*)d_in[6];
    const u8* boot_mask  = (const u8*)d_in[7];
    float* out = (float*)d_out;
    float* ws  = (float*)d_ws;

    long ws_floats = (long)(ws_size / 4);
    int Ec = (int)((ws_floats - (long)W_ENT) / (long)(B * CAP * 2));
    if (Ec > E) Ec = E;
    if (Ec < 1) Ec = 1;

    u16* af = (u16*)(ws + W_AF);
    u32* pb = (u32*)(ws + W_PB);
    u32* ps = (u32*)(ws + W_PS);
    u32* pn = (u32*)(ws + W_PN);
    int* cnt_buf = (int*)(ws + W_CNTB);
    uint2* ent_buf = (uint2*)(ws + W_ENT);

    // zero scores + cnt + unc + cnt_buf (contiguous 2134016 floats = 2084*1024)
    k_zero<<<NZERO / 1024, 256, 0, stream>>>((float4*)(ws + W_SCORES));
    k_pack<<<dim3((E * B) / 64, Q / 512, 3), 256, 0, stream>>>(
        boot_mask, score_mask, mask_n, pb, ps, pn);
    k_afrag<<<E * B, 128, 0, stream>>>(teacher, mask_t, af);
    k_invn<<<dim3(E, 4), 256, 0, stream>>>(neg, pn, ws + W_INVN);
    k_logits<<<dim3(B, 4), 256, 0, stream>>>(query, key, neg, out);
    k_rowstats<<<B, 256, 0, stream>>>(out, ws + W_MOCO, ws + W_NLSE);

    for (int e0 = 0; e0 < E; e0 += Ec) {
        int ecnt = (E - e0 < Ec) ? (E - e0) : Ec;
        if (e0 > 0)
            k_zero<<<32, 256, 0, stream>>>((float4*)(ws + W_CNTB));  // cnt_buf
        k_fused<<<dim3(Q / 64, ecnt), 256, 0, stream>>>(
            af, neg, pn, ws + W_INVN, pb, ps, ws + W_UNC, ent_buf, cnt_buf, e0);
        k_scores<<<B, 512, 0, stream>>>(ent_buf, cnt_buf,
                                        ws + W_SCORES, ws + W_CNT, ecnt);
    }

    k_median<<<1, 1024, 0, stream>>>(ws + W_UNC, ws + W_UB);
    k_select<<<dim3(B, 2), 256, 0, stream>>>(out, ws + W_SCORES, ws + W_CNT,
                                             ws + W_UNC, ws + W_UB,
                                             ws + W_NLSE, ws + W_EASY, ws + W_HARD);
    k_scalars<<<1, 256, 0, stream>>>(ws + W_MOCO, ws + W_EASY, ws + W_HARD, out);
}

// Round 9
// 1428.445 us; speedup vs baseline: 1.0510x; 1.0342x over previous
//
#include <hip/hip_runtime.h>
#include <cmath>

typedef unsigned char u8;
typedef unsigned short u16;
typedef unsigned int u32;
typedef __attribute__((ext_vector_type(8))) short s8v;    // 8 bf16 = 4 VGPRs
typedef __attribute__((ext_vector_type(4))) float f32x4;  // MFMA acc

#define B 256
#define F 128
#define Q 4096
#define E 128
#define QW 128               // Q/32 words per row
#define INV_TAU 5.0f
#define CAP 256              // compact entries per (e,b); binomial(4096,1/32) max ~180

// ---- ws layout (offsets in floats) ----
#define W_SCORES 0u            // B*Q (z=0 slab)
#define W_SC2    1048576u      // B*Q (z=1 slab)
#define W_CNT    2097152u      // B*Q
#define W_CN2    3145728u      // B*Q
#define W_UNC    4194304u      // 4096
#define W_CNTB   4198400u      // E*B ints = 32768
#define W_NLSE   4231168u      // 256
#define W_MOCO   4231424u
#define W_EASY   4231680u
#define W_HARD   4231936u
#define W_UB     4232192u      // 256 pad
#define W_INVN   4232448u      // E*Q = 524288
#define W_AF     4756736u      // bf16 E*B*F -> 2097152 floats
#define W_PB     6853888u      // packed boot  E*QW*B words = 4194304
#define W_PS     11048192u     // packed smask E*QW*B words = 4194304
#define W_PN     15242496u     // packed mask_n E*QW*F words = 2097152
#define W_BF     17339648u     // bf16 B-fragments E*Q*F -> 67108864 floats
#define W_ENT    84448512u     // Ec*256*CAP uint2 -> Ec*131072 floats
#define NZERO    4231168u      // zero range: SCORES..CNTB end (4132*1024)

// ---- out layout (floats) ----
#define O_MOCO   0u
#define O_LOGITS 1u            // (B, Q+1)
#define O_ELOSS  1048833u
#define O_EMASK  1048834u      // (B, Q)
#define O_HLOSS  2097410u
#define O_HMASK  2097411u      // (B, Q)

static __device__ __forceinline__ u16 f2bf(float x) {
    unsigned int u = __builtin_bit_cast(unsigned int, x);
    unsigned int r = (u + 0x7FFFu + ((u >> 16) & 1u)) >> 16;
    return (u16)r;
}

__global__ void k_zero(float4* __restrict__ p) {
    p[(size_t)blockIdx.x * 256 + threadIdx.x] = make_float4(0.f, 0.f, 0.f, 0.f);
}

// ---- bit-pack all three masks; z selects tensor. out[e][qw][r] transposed words.
__global__ void __launch_bounds__(256) k_pack(const u8* __restrict__ boot,
                                              const u8* __restrict__ smask,
                                              const u8* __restrict__ maskn,
                                              u32* __restrict__ pb, u32* __restrict__ ps,
                                              u32* __restrict__ pn) {
    int z = blockIdx.z;
    int Rin = (z == 2) ? F : B;
    if (z == 2 && blockIdx.x >= 2048) return;
    const u8* in = (z == 0) ? boot : (z == 1) ? smask : maskn;
    u32* out = (z == 0) ? pb : (z == 1) ? ps : pn;
    __shared__ u32 lds[64 * 133];
    int t = threadIdx.x;
    int r0 = blockIdx.x * 64;
    int q0 = blockIdx.y * 512;
    int qw0 = q0 >> 5;
    #pragma unroll
    for (int i = 0; i < 8; i++) {
        int w = i * 256 + t;
        int row = w >> 5, c = w & 31;
        uint4 v = *(const uint4*)&in[(size_t)(r0 + row) * Q + q0 + c * 16];
        int base = row * 133 + c * 4;
        lds[base] = v.x; lds[base + 1] = v.y; lds[base + 2] = v.z; lds[base + 3] = v.w;
    }
    __syncthreads();
    int e = r0 / Rin, rr = r0 % Rin;
    #pragma unroll
    for (int k = 0; k < 4; k++) {
        int qw = (t >> 6) + k * 4;
        int r = t & 63;
        u32 w = 0;
        #pragma unroll
        for (int j = 0; j < 8; j++) {
            u32 u = lds[r * 133 + qw * 8 + j];
            w |= ((u & 1u) | ((u >> 7) & 2u) | ((u >> 14) & 4u) | ((u >> 21) & 8u)) << (j * 4);
        }
        out[((size_t)e * QW + qw0 + qw) * Rin + rr + r] = w;
    }
}

// 256 blocks (e, half): 128 rows each, 16 thr/row, shfl row-reduce -> bf16 A-frags
__global__ void __launch_bounds__(256) k_afrag(const float* __restrict__ teacher,
                                               const u8* __restrict__ mask_t,
                                               u16* __restrict__ af) {
    int e = blockIdx.x >> 1, h = blockIdx.x & 1;
    int t = threadIdx.x;
    int lane16 = t & 15;
    int f0 = lane16 * 8;
    #pragma unroll
    for (int it = 0; it < 8; it++) {
        int b = h * 128 + it * 16 + (t >> 4);
        float4 x0 = *(const float4*)&teacher[b * F + f0];
        float4 x1 = *(const float4*)&teacher[b * F + f0 + 4];
        const u8* mk = &mask_t[((size_t)e * B + b) * F + f0];
        float v[8];
        v[0] = mk[0] ? 0.f : x0.x; v[1] = mk[1] ? 0.f : x0.y;
        v[2] = mk[2] ? 0.f : x0.z; v[3] = mk[3] ? 0.f : x0.w;
        v[4] = mk[4] ? 0.f : x1.x; v[5] = mk[5] ? 0.f : x1.y;
        v[6] = mk[6] ? 0.f : x1.z; v[7] = mk[7] ? 0.f : x1.w;
        float ss = 0.f;
        #pragma unroll
        for (int j = 0; j < 8; j++) ss = fmaf(v[j], v[j], ss);
        ss += __shfl_xor(ss, 1); ss += __shfl_xor(ss, 2);
        ss += __shfl_xor(ss, 4); ss += __shfl_xor(ss, 8);
        float inv = 1.f / fmaxf(sqrtf(ss), 1e-12f);
        u16 o[8];
        #pragma unroll
        for (int j = 0; j < 8; j++) o[j] = f2bf(v[j] * inv);
        int bg = b >> 4, m = b & 15;
        int kb = f0 >> 5, quad = (f0 >> 3) & 3;
        int lane = quad * 16 + m;
        *(s8v*)&af[((((size_t)e * 16 + bg) * 4 + kb) * 64 + lane) * 8] = *(const s8v*)o;
    }
}

// per (e, 1024-q block): 1/(TAU*||masked neg col||)
__global__ void __launch_bounds__(256) k_invn(const float* __restrict__ neg,
                                              const u32* __restrict__ pn,
                                              float* __restrict__ invn) {
    __shared__ u32 lds[32 * 128];
    int e = blockIdx.x, t = threadIdx.x;
    int qblk = blockIdx.y;
    size_t base = ((size_t)e * QW + qblk * 32) * F;
    #pragma unroll
    for (int k = 0; k < 16; k++) lds[t + 256 * k] = pn[base + t + 256 * k];
    __syncthreads();
    int q0 = qblk * 1024 + t * 4;
    int qwl = (t * 4) >> 5;
    int sh = (t * 4) & 31;
    float s0 = 0.f, s1 = 0.f, s2 = 0.f, s3 = 0.f;
    #pragma unroll 4
    for (int f = 0; f < F; f++) {
        float4 v = *(const float4*)&neg[(size_t)f * Q + q0];
        u32 w = lds[qwl * 128 + f] >> sh;
        if (!(w & 1u)) s0 = fmaf(v.x, v.x, s0);
        if (!(w & 2u)) s1 = fmaf(v.y, v.y, s1);
        if (!(w & 4u)) s2 = fmaf(v.z, v.z, s2);
        if (!(w & 8u)) s3 = fmaf(v.w, v.w, s3);
    }
    float4 r;
    r.x = INV_TAU / fmaxf(sqrtf(s0), 1e-12f);
    r.y = INV_TAU / fmaxf(sqrtf(s1), 1e-12f);
    r.z = INV_TAU / fmaxf(sqrtf(s2), 1e-12f);
    r.w = INV_TAU / fmaxf(sqrtf(s3), 1e-12f);
    *(float4*)&invn[(size_t)e * Q + q0] = r;
}

// per (e, 64-q slab): build bf16 B fragments (masked, normalized) with coalesced
// float4 neg reads + LDS transpose -> 16B fragment dumps
__global__ void __launch_bounds__(256) k_bprep(const float* __restrict__ neg,
                                               const u32* __restrict__ pn,
                                               const float* __restrict__ invn,
                                               u16* __restrict__ bf) {
    __shared__ u16 lf[8192];               // 16 KB fragment tile
    __shared__ u32 pnl[2][128];
    __shared__ float invl[64];
    int e = blockIdx.x, qb = blockIdx.y, t = threadIdx.x;
    int q0 = qb * 64, qw0 = qb * 2;
    if (t < 128) pnl[0][t] = pn[((size_t)e * QW + qw0) * F + t];
    else pnl[1][t - 128] = pn[((size_t)e * QW + qw0 + 1) * F + t - 128];
    if (t < 16) *(float4*)&invl[t * 4] = *(const float4*)&invn[(size_t)e * Q + q0 + t * 4];
    __syncthreads();
    #pragma unroll
    for (int it = 0; it < 8; it++) {
        int idx = it * 256 + t;
        int f = idx >> 4, qq = (idx & 15) * 4;
        float4 x = *(const float4*)&neg[(size_t)f * Q + q0 + qq];
        int kb = f >> 5, quad = (f >> 3) & 3, j = f & 7;
        float xv[4] = {x.x, x.y, x.z, x.w};
        #pragma unroll
        for (int c = 0; c < 4; c++) {
            int ql = qq + c;
            u32 bit = (pnl[ql >> 5][f] >> (ql & 31)) & 1u;
            float v = bit ? 0.f : xv[c] * invl[ql];
            int qg = ql >> 4;
            int lane = quad * 16 + (ql & 15);
            lf[(((qg * 4 + kb) * 64) + lane) * 8 + j] = f2bf(v);
        }
    }
    __syncthreads();
    size_t gb = ((size_t)e * 256 + qb * 4) * 4 * 64 * 8;   // base of this slab's frags
    #pragma unroll
    for (int it = 0; it < 4; it++) {
        int s = it * 256 + t;                              // flat (qg*4+kb)*64+lane
        *(s8v*)&bf[gb + (size_t)s * 8] = *(const s8v*)&lf[s * 8];
    }
}

// Fused: per (e, 64-q slab): direct-load fragments, MFMA, exp, column softmax+
// entropy (boot), popc-reserved extraction of (q, exp) smask entries.
__global__ void __launch_bounds__(256) k_fused(
        const u16* __restrict__ af, const u16* __restrict__ bf,
        const u32* __restrict__ pb, const u32* __restrict__ ps,
        float* __restrict__ unc, uint2* __restrict__ ent_buf,
        int* __restrict__ cnt_buf, int e0) {
    __shared__ u32 bw[2][256], sw[2][256];                    // 4 KB
    __shared__ float sstat[4][64], cstat[4][64], estat[4][64];
    __shared__ float carr[64];
    __shared__ int sbase[256];

    int qb = blockIdx.x;                  // 0..63 (64-q slab)
    int el = blockIdx.y, e = e0 + el;
    int t = threadIdx.x;
    int q0 = qb * 64;
    int qw0 = qb * 2;

    bw[0][t] = pb[((size_t)e * QW + qw0) * B + t];
    bw[1][t] = pb[((size_t)e * QW + qw0 + 1) * B + t];
    sw[0][t] = ps[((size_t)e * QW + qw0) * B + t];
    sw[1][t] = ps[((size_t)e * QW + qw0 + 1) * B + t];
    __syncthreads();

    // ---- MFMA: wave w covers b in [w*64, w*64+64), 4 qg columns ----
    int wave = t >> 6, lane = t & 63;
    int colb = lane & 15, quad = lane >> 4;
    const s8v* bfv = (const s8v*)&bf[((size_t)e * 256 + qb * 4) * 4 * 64 * 8];
    f32x4 acc[4][4];
    #pragma unroll
    for (int bgi = 0; bgi < 4; bgi++) {
        int bg = wave * 4 + bgi;
        s8v a[4];
        #pragma unroll
        for (int kb = 0; kb < 4; kb++)
            a[kb] = *(const s8v*)&af[((((size_t)e * 16 + bg) * 4 + kb) * 64 + lane) * 8];
        #pragma unroll
        for (int qg = 0; qg < 4; qg++) {
            f32x4 c4 = {0.f, 0.f, 0.f, 0.f};
            #pragma unroll
            for (int kb = 0; kb < 4; kb++) {
                s8v bv = bfv[(qg * 4 + kb) * 64 + lane];
                c4 = __builtin_amdgcn_mfma_f32_16x16x32_bf16(a[kb], bv, c4, 0, 0, 0);
            }
            acc[bgi][qg] = c4;
        }
    }

    // ---- exp in place (M = 0 safe: |sim*INV_TAU| <= ~5.2) ----
    #pragma unroll
    for (int bgi = 0; bgi < 4; bgi++)
        #pragma unroll
        for (int qg = 0; qg < 4; qg++)
            #pragma unroll
            for (int r = 0; r < 4; r++)
                acc[bgi][qg][r] = __expf(acc[bgi][qg][r]);

    // ---- column (boot) exp-sum + count ----
    float sloc[4] = {0.f, 0.f, 0.f, 0.f}, cloc[4] = {0.f, 0.f, 0.f, 0.f};
    #pragma unroll
    for (int bgi = 0; bgi < 4; bgi++) {
        int b0 = (wave * 4 + bgi) * 16 + quad * 4;
        uint4 w0 = *(const uint4*)&bw[0][b0];
        uint4 w1 = *(const uint4*)&bw[1][b0];
        u32 W0[4] = {w0.x, w0.y, w0.z, w0.w};
        u32 W1[4] = {w1.x, w1.y, w1.z, w1.w};
        #pragma unroll
        for (int r = 0; r < 4; r++)
            #pragma unroll
            for (int qg = 0; qg < 4; qg++) {
                u32 w = (qg & 2) ? W1[r] : W0[r];
                int bpos = (qg & 1) * 16 + colb;
                if ((w >> bpos) & 1u) {
                    sloc[qg] += acc[bgi][qg][r];
                    cloc[qg] += 1.f;
                }
            }
    }
    #pragma unroll
    for (int qg = 0; qg < 4; qg++) {
        sloc[qg] += __shfl_xor(sloc[qg], 16); sloc[qg] += __shfl_xor(sloc[qg], 32);
        cloc[qg] += __shfl_xor(cloc[qg], 16); cloc[qg] += __shfl_xor(cloc[qg], 32);
    }
    if (quad == 0)
        #pragma unroll
        for (int qg = 0; qg < 4; qg++) {
            sstat[wave][qg * 16 + colb] = sloc[qg];
            cstat[wave][qg * 16 + colb] = cloc[qg];
        }
    __syncthreads();
    float invS[4];
    #pragma unroll
    for (int qg = 0; qg < 4; qg++) {
        int c = qg * 16 + colb;
        float S = sstat[0][c] + sstat[1][c] + sstat[2][c] + sstat[3][c];
        invS[qg] = 1.f / fmaxf(S, 1e-30f);
    }
    if (wave == 0 && quad == 0)
        #pragma unroll
        for (int qg = 0; qg < 4; qg++) {
            int c = qg * 16 + colb;
            carr[c] = cstat[0][c] + cstat[1][c] + cstat[2][c] + cstat[3][c];
        }

    // ---- entropy (reuse exps) ----
    const float P0 = 1e-7f;
    const float C0 = 1.61180954e-6f;      // -P0*log(P0)
    float eloc[4] = {0.f, 0.f, 0.f, 0.f};
    #pragma unroll
    for (int bgi = 0; bgi < 4; bgi++) {
        int b0 = (wave * 4 + bgi) * 16 + quad * 4;
        uint4 w0 = *(const uint4*)&bw[0][b0];
        uint4 w1 = *(const uint4*)&bw[1][b0];
        u32 W0[4] = {w0.x, w0.y, w0.z, w0.w};
        u32 W1[4] = {w1.x, w1.y, w1.z, w1.w};
        #pragma unroll
        for (int r = 0; r < 4; r++)
            #pragma unroll
            for (int qg = 0; qg < 4; qg++) {
                u32 w = (qg & 2) ? W1[r] : W0[r];
                int bpos = (qg & 1) * 16 + colb;
                if ((w >> bpos) & 1u) {
                    float p = acc[bgi][qg][r] * invS[qg] + P0;
                    eloc[qg] -= p * __logf(p);
                } else {
                    eloc[qg] += C0;
                }
            }
    }
    #pragma unroll
    for (int qg = 0; qg < 4; qg++) {
        eloc[qg] += __shfl_xor(eloc[qg], 16); eloc[qg] += __shfl_xor(eloc[qg], 32);
    }
    if (quad == 0)
        #pragma unroll
        for (int qg = 0; qg < 4; qg++) estat[wave][qg * 16 + colb] = eloc[qg];

    // ---- extraction reservation (per-b popc over both words) ----
    {
        u32 a0 = sw[0][t], a1 = sw[1][t];
        int n = __popc(a0) + __popc(a1);
        int base = 0;
        if (n) base = atomicAdd(&cnt_buf[el * B + t], n);
        sbase[t] = base;
    }
    __syncthreads();

    if (t < 64) {
        float tot = estat[0][t] + estat[1][t] + estat[2][t] + estat[3][t];
        atomicAdd(&unc[q0 + t], tot / fmaxf(carr[t], 1.f));
    }

    // ---- scatter compact (q, exp) entries; word-level early-out (3% density) ----
    u32 cmask = 0x00010001u << colb;
    #pragma unroll
    for (int bgi = 0; bgi < 4; bgi++) {
        int b0 = (wave * 4 + bgi) * 16 + quad * 4;
        uint4 s0 = *(const uint4*)&sw[0][b0];
        uint4 s1 = *(const uint4*)&sw[1][b0];
        u32 S0[4] = {s0.x, s0.y, s0.z, s0.w};
        u32 S1[4] = {s1.x, s1.y, s1.z, s1.w};
        #pragma unroll
        for (int r = 0; r < 4; r++) {
            if (!((S0[r] | S1[r]) & cmask)) continue;
            int bs = sbase[b0 + r];
            int p0 = __popc(S0[r]);
            #pragma unroll
            for (int qg = 0; qg < 4; qg++) {
                int bpos = (qg & 1) * 16 + colb;
                u32 w = (qg & 2) ? S1[r] : S0[r];
                if ((w >> bpos) & 1u) {
                    int rank = __popc(w & ((1u << bpos) - 1u)) + ((qg & 2) ? p0 : 0);
                    int pos = bs + rank;
                    if (pos < CAP) {
                        uint2 en;
                        en.x = (unsigned)(q0 + qg * 16 + colb);
                        en.y = __builtin_bit_cast(unsigned, acc[bgi][qg][r]);
                        ent_buf[((size_t)(el * B + b0 + r)) * CAP + pos] = en;
                    }
                }
            }
        }
    }
}

// grid (b, z): z-half of ensembles -> row softmax scatter into slab z
__global__ void __launch_bounds__(512) k_scores(
        const uint2* __restrict__ ent_buf, const int* __restrict__ cnt_buf,
        float* __restrict__ sacc, float* __restrict__ cacc, int ecnt) {
    __shared__ float srow[Q];
    __shared__ float crow[Q];
    __shared__ int cl[64];
    int b = blockIdx.x, z = blockIdx.y, t = threadIdx.x;
    int half = (ecnt + 1) >> 1;
    int el0 = z * half;
    int nel = ecnt - el0; if (nel > half) nel = half; if (nel < 0) nel = 0;
    #pragma unroll
    for (int j = 0; j < 8; j++) { srow[t + 512 * j] = 0.f; crow[t + 512 * j] = 0.f; }
    if (t < nel) {
        int c = cnt_buf[(el0 + t) * B + b];
        cl[t] = (c > CAP) ? CAP : c;
    }
    __syncthreads();
    int wave = t >> 6, lane = t & 63;
    for (int i = wave; i < nel; i += 8) {
        int c = cl[i];
        if (c == 0) continue;
        const uint2* p = ent_buf + (size_t)((el0 + i) * B + b) * CAP;
        uint2 ev[4]; int ne = 0;
        float s = 0.f;
        for (int k = lane; k < c; k += 64) {
            ev[ne] = p[k];
            s += __builtin_bit_cast(float, ev[ne].y);
            ne++;
        }
        #pragma unroll
        for (int off = 32; off > 0; off >>= 1) s += __shfl_xor(s, off);
        float iS = 1.f / fmaxf(s, 1e-30f);
        for (int k = 0; k < ne; k++) {
            atomicAdd(&srow[ev[k].x], __builtin_bit_cast(float, ev[k].y) * iS);
            atomicAdd(&crow[ev[k].x], 1.f);
        }
    }
    __syncthreads();
    float* sa = sacc + (size_t)z * B * Q;
    float* ca = cacc + (size_t)z * B * Q;
    #pragma unroll
    for (int j = 0; j < 8; j++) {
        int q = t + 512 * j;
        sa[(size_t)b * Q + q] += srow[q];
        ca[(size_t)b * Q + q] += crow[q];
    }
}

// (b, seg) grid: logits slab of 1024 q; seg 0 also writes pos logit
__global__ void k_logits(const float* __restrict__ query, const float* __restrict__ key,
                         const float* __restrict__ neg, float* __restrict__ out) {
    __shared__ float qrow[F];
    __shared__ float red[256];
    int b = blockIdx.x, seg = blockIdx.y, t = threadIdx.x;
    if (t < F) qrow[t] = query[b * F + t];
    __syncthreads();
    int q0 = seg * 1024 + t * 4;
    float4 acc = make_float4(0.f, 0.f, 0.f, 0.f);
    for (int f = 0; f < F; f++) {
        float a = qrow[f];
        float4 v = *(const float4*)&neg[(size_t)f * Q + q0];
        acc.x = fmaf(a, v.x, acc.x);
        acc.y = fmaf(a, v.y, acc.y);
        acc.z = fmaf(a, v.z, acc.z);
        acc.w = fmaf(a, v.w, acc.w);
    }
    float* row = out + O_LOGITS + (size_t)b * (Q + 1);
    row[1 + q0]     = acc.x * INV_TAU;
    row[1 + q0 + 1] = acc.y * INV_TAU;
    row[1 + q0 + 2] = acc.z * INV_TAU;
    row[1 + q0 + 3] = acc.w * INV_TAU;
    if (seg == 0) {
        float pp = (t < F) ? qrow[t] * key[b * F + t] : 0.f;
        red[t] = pp;
        __syncthreads();
        for (int s = 128; s > 0; s >>= 1) { if (t < s) red[t] += red[t + s]; __syncthreads(); }
        if (t == 0) row[0] = red[0] * INV_TAU;
    }
}

// block per b: moco part (full-row LSE - z0) and neg-only LSE
__global__ void k_rowstats(const float* __restrict__ out, float* __restrict__ moco_part,
                           float* __restrict__ nlse) {
    __shared__ float red[256];
    int b = blockIdx.x, t = threadIdx.x;
    const float* row = out + O_LOGITS + (size_t)b * (Q + 1);
    float m = -INFINITY, mn = -INFINITY;
    for (int j = 0; j < 17; j++) {
        int i = t + 256 * j;
        if (i < Q + 1) { float zz = row[i]; m = fmaxf(m, zz); if (i >= 1) mn = fmaxf(mn, zz); }
    }
    red[t] = m; __syncthreads();
    for (int s = 128; s > 0; s >>= 1) { if (t < s) red[t] = fmaxf(red[t], red[t + s]); __syncthreads(); }
    float M = red[0]; __syncthreads();
    red[t] = mn; __syncthreads();
    for (int s = 128; s > 0; s >>= 1) { if (t < s) red[t] = fmaxf(red[t], red[t + s]); __syncthreads(); }
    float Mn = red[0]; __syncthreads();
    float s1 = 0.f, s2 = 0.f;
    for (int j = 0; j < 17; j++) {
        int i = t + 256 * j;
        if (i < Q + 1) { float zz = row[i]; s1 += expf(zz - M); if (i >= 1) s2 += expf(zz - Mn); }
    }
    red[t] = s1; __syncthreads();
    for (int s = 128; s > 0; s >>= 1) { if (t < s) red[t] += red[t + s]; __syncthreads(); }
    float S = red[0]; __syncthreads();
    red[t] = s2; __syncthreads();
    for (int s = 128; s > 0; s >>= 1) { if (t < s) red[t] += red[t + s]; __syncthreads(); }
    float Sn = red[0];
    if (t == 0) { moco_part[b] = M + logf(S) - row[0]; nlse[b] = Mn + logf(Sn); }
}

// normalize unc (/E), bitonic sort 4096, median per np.quantile 'linear'
__global__ void k_median(float* __restrict__ unc, float* __restrict__ ubp) {
    __shared__ float sd[4096];
    int t = threadIdx.x;
    #pragma unroll
    for (int j = 0; j < 4; j++) {
        int q = t + 1024 * j;
        float u = unc[q] * (1.f / 128.f);
        unc[q] = u; sd[q] = u;
    }
    __syncthreads();
    for (int k = 2; k <= 4096; k <<= 1) {
        for (int j = k >> 1; j > 0; j >>= 1) {
            #pragma unroll
            for (int base = 0; base < 4; base++) {
                int i = t + 1024 * base;
                int ixj = i ^ j;
                if (ixj > i) {
                    bool up = ((i & k) == 0);
                    float x = sd[i], y = sd[ixj];
                    if ((x > y) == up) { sd[i] = y; sd[ixj] = x; }
                }
            }
            __syncthreads();
        }
    }
    if (t == 0) { float a = sd[2047], b2 = sd[2048]; ubp[0] = a + 0.5f * (b2 - a); }
}

// per (b, mode): argmax of scores among allowed q (lowest-index ties), mask + loss
__global__ void k_select(float* __restrict__ out, const float* __restrict__ sacc,
                         const float* __restrict__ cacc,
                         const float* __restrict__ unc, const float* __restrict__ ubp,
                         const float* __restrict__ nlse, float* __restrict__ easy_part,
                         float* __restrict__ hard_part) {
    __shared__ float rv[256];
    __shared__ int ri[256];
    __shared__ int bshare;
    int b = blockIdx.x, mode = blockIdx.y, t = threadIdx.x;
    float ub = ubp[0];
    float bv = -INFINITY; int bidx = Q;
    #pragma unroll
    for (int j = 0; j < 16; j++) {
        int q = t + 256 * j;
        float u = unc[q];
        bool ok = (mode == 0) ? (u <= ub) : (u >= ub);
        if (ok) {
            size_t ix = (size_t)b * Q + q;
            float s = sacc[ix] + sacc[(size_t)B * Q + ix];
            float c = cacc[ix] + cacc[(size_t)B * Q + ix];
            float v = s / fmaxf(c, 1.f);
            if (v > bv || (v == bv && q < bidx)) { bv = v; bidx = q; }
        }
    }
    rv[t] = bv; ri[t] = bidx; __syncthreads();
    for (int s = 128; s > 0; s >>= 1) {
        if (t < s) {
            float v2 = rv[t + s]; int i2 = ri[t + s];
            if (v2 > rv[t] || (v2 == rv[t] && i2 < ri[t])) { rv[t] = v2; ri[t] = i2; }
        }
        __syncthreads();
    }
    if (t == 0) {
        int best = ri[0]; bshare = best;
        float zz = out[O_LOGITS + (size_t)b * (Q + 1) + 1 + best];
        float loss = nlse[b] - zz;
        (mode == 0 ? easy_part : hard_part)[b] = loss;
    }
    __syncthreads();
    int best = bshare;
    float* mrow = out + (mode == 0 ? O_EMASK : O_HMASK) + (size_t)b * Q;
    #pragma unroll
    for (int j = 0; j < 16; j++) { int q = t + 256 * j; mrow[q] = (q == best) ? 1.f : 0.f; }
}

__global__ void k_scalars(const float* __restrict__ moco, const float* __restrict__ easyp,
                          const float* __restrict__ hardp, float* __restrict__ out) {
    __shared__ float red[256];
    int t = threadIdx.x;
    red[t] = moco[t]; __syncthreads();
    for (int s = 128; s > 0; s >>= 1) { if (t < s) red[t] += red[t + s]; __syncthreads(); }
    if (t == 0) out[O_MOCO] = red[0] / 256.f;
    __syncthreads();
    red[t] = easyp[t]; __syncthreads();
    for (int s = 128; s > 0; s >>= 1) { if (t < s) red[t] += red[t + s]; __syncthreads(); }
    if (t == 0) out[O_ELOSS] = red[0] / 256.f;
    __syncthreads();
    red[t] = hardp[t]; __syncthreads();
    for (int s = 128; s > 0; s >>= 1) { if (t < s) red[t] += red[t + s]; __syncthreads(); }
    if (t == 0) out[O_HLOSS] = red[0] / 256.f;
}

extern "C" void kernel_launch(void* const* d_in, const int* in_sizes, int n_in,
                              void* d_out, int out_size, void* d_ws, size_t ws_size,
                              hipStream_t stream) {
    const float* query   = (const float*)d_in[0];
    const float* key     = (const float*)d_in[1];
    const float* teacher = (const float*)d_in[2];
    const float* neg     = (const float*)d_in[3];
    const u8* mask_t     = (const u8*)d_in[4];
    const u8* mask_n     = (const u8*)d_in[5];
    const u8* score_mask = (const u8*)d_in[6];
    const u8* boot_mask  = (const u8*)d_in[7];
    float* out = (float*)d_out;
    float* ws  = (float*)d_ws;

    long ws_floats = (long)(ws_size / 4);
    int Ec = (int)((ws_floats - (long)W_ENT) / (long)(B * CAP * 2));
    if (Ec > E) Ec = E;
    if (Ec < 1) Ec = 1;

    u16* af = (u16*)(ws + W_AF);
    u32* pb = (u32*)(ws + W_PB);
    u32* ps = (u32*)(ws + W_PS);
    u32* pn = (u32*)(ws + W_PN);
    u16* bfr = (u16*)(ws + W_BF);
    int* cnt_buf = (int*)(ws + W_CNTB);
    uint2* ent_buf = (uint2*)(ws + W_ENT);

    // zero scores x2 + cnt x2 + unc + cnt_buf (contiguous 4231168 floats)
    k_zero<<<NZERO / 1024, 256, 0, stream>>>((float4*)(ws + W_SCORES));
    k_pack<<<dim3((E * B) / 64, Q / 512, 3), 256, 0, stream>>>(
        boot_mask, score_mask, mask_n, pb, ps, pn);
    k_afrag<<<E * 2, 256, 0, stream>>>(teacher, mask_t, af);
    k_invn<<<dim3(E, 4), 256, 0, stream>>>(neg, pn, ws + W_INVN);
    k_bprep<<<dim3(E, Q / 64), 256, 0, stream>>>(neg, pn, ws + W_INVN, bfr);
    k_logits<<<dim3(B, 4), 256, 0, stream>>>(query, key, neg, out);
    k_rowstats<<<B, 256, 0, stream>>>(out, ws + W_MOCO, ws + W_NLSE);

    for (int e0 = 0; e0 < E; e0 += Ec) {
        int ecnt = (E - e0 < Ec) ? (E - e0) : Ec;
        if (e0 > 0)
            k_zero<<<32, 256, 0, stream>>>((float4*)(ws + W_CNTB));  // cnt_buf
        k_fused<<<dim3(Q / 64, ecnt), 256, 0, stream>>>(
            af, bfr, pb, ps, ws + W_UNC, ent_buf, cnt_buf, e0);
        k_scores<<<dim3(B, 2), 512, 0, stream>>>(ent_buf, cnt_buf,
                                                 ws + W_SCORES, ws + W_CNT, ecnt);
    }

    k_median<<<1, 1024, 0, stream>>>(ws + W_UNC, ws + W_UB);
    k_select<<<dim3(B, 2), 256, 0, stream>>>(out, ws + W_SCORES, ws + W_CNT,
                                             ws + W_UNC, ws + W_UB,
                                             ws + W_NLSE, ws + W_EASY, ws + W_HARD);
    k_scalars<<<1, 256, 0, stream>>>(ws + W_MOCO, ws + W_EASY, ws + W_HARD, out);
}

// Round 10
// 1358.763 us; speedup vs baseline: 1.1049x; 1.0513x over previous
//
#include <hip/hip_runtime.h>
#include <cmath>

typedef unsigned char u8;
typedef unsigned short u16;
typedef unsigned int u32;
typedef __attribute__((ext_vector_type(8))) short s8v;    // 8 bf16 = 4 VGPRs
typedef __attribute__((ext_vector_type(4))) float f32x4;  // MFMA acc

#define B 256
#define F 128
#define Q 4096
#define E 128
#define QW 128               // Q/32 words per row
#define INV_TAU 5.0f
#define CAP 256              // compact entries per (e,b); binomial(4096,1/32) max ~180

// ---- ws layout (offsets in floats) ----
#define W_SCORES 0u            // B*Q (z=0 slab)
#define W_SC2    1048576u      // B*Q (z=1 slab)
#define W_CNT    2097152u      // B*Q
#define W_CN2    3145728u      // B*Q
#define W_UNC    4194304u      // 4096
#define W_CNTB   4198400u      // E*B ints = 32768
#define W_NLSE   4231168u      // 256
#define W_MOCO   4231424u
#define W_EASY   4231680u
#define W_HARD   4231936u
#define W_UB     4232192u      // 256 pad
#define W_INVN   4232448u      // E*Q = 524288
#define W_AF     4756736u      // bf16 E*B*F -> 2097152 floats
#define W_PB     6853888u      // packed boot  E*QW*B words = 4194304
#define W_PS     11048192u     // packed smask E*QW*B words = 4194304
#define W_PN     15242496u     // packed mask_n E*QW*F words = 2097152
#define W_BF     17339648u     // bf16 B-fragments E*Q*F -> 67108864 floats
#define W_ENT    84448512u     // Ec*256*CAP uint2 -> Ec*131072 floats
#define NZERO    4231168u      // zero range: SCORES..CNTB end (4132*1024)

// ---- out layout (floats) ----
#define O_MOCO   0u
#define O_LOGITS 1u            // (B, Q+1)
#define O_ELOSS  1048833u
#define O_EMASK  1048834u      // (B, Q)
#define O_HLOSS  2097410u
#define O_HMASK  2097411u      // (B, Q)

static __device__ __forceinline__ u16 f2bf(float x) {
    unsigned int u = __builtin_bit_cast(unsigned int, x);
    unsigned int r = (u + 0x7FFFu + ((u >> 16) & 1u)) >> 16;
    return (u16)r;
}

__global__ void k_zero(float4* __restrict__ p) {
    p[(size_t)blockIdx.x * 256 + threadIdx.x] = make_float4(0.f, 0.f, 0.f, 0.f);
}

// ---- bit-pack all three masks; z selects tensor. out[e][qw][r] transposed words.
__global__ void __launch_bounds__(256) k_pack(const u8* __restrict__ boot,
                                              const u8* __restrict__ smask,
                                              const u8* __restrict__ maskn,
                                              u32* __restrict__ pb, u32* __restrict__ ps,
                                              u32* __restrict__ pn) {
    int z = blockIdx.z;
    int Rin = (z == 2) ? F : B;
    if (z == 2 && blockIdx.x >= 2048) return;
    const u8* in = (z == 0) ? boot : (z == 1) ? smask : maskn;
    u32* out = (z == 0) ? pb : (z == 1) ? ps : pn;
    __shared__ u32 lds[64 * 133];
    int t = threadIdx.x;
    int r0 = blockIdx.x * 64;
    int q0 = blockIdx.y * 512;
    int qw0 = q0 >> 5;
    #pragma unroll
    for (int i = 0; i < 8; i++) {
        int w = i * 256 + t;
        int row = w >> 5, c = w & 31;
        uint4 v = *(const uint4*)&in[(size_t)(r0 + row) * Q + q0 + c * 16];
        int base = row * 133 + c * 4;
        lds[base] = v.x; lds[base + 1] = v.y; lds[base + 2] = v.z; lds[base + 3] = v.w;
    }
    __syncthreads();
    int e = r0 / Rin, rr = r0 % Rin;
    #pragma unroll
    for (int k = 0; k < 4; k++) {
        int qw = (t >> 6) + k * 4;
        int r = t & 63;
        u32 w = 0;
        #pragma unroll
        for (int j = 0; j < 8; j++) {
            u32 u = lds[r * 133 + qw * 8 + j];
            w |= ((u & 1u) | ((u >> 7) & 2u) | ((u >> 14) & 4u) | ((u >> 21) & 8u)) << (j * 4);
        }
        out[((size_t)e * QW + qw0 + qw) * Rin + rr + r] = w;
    }
}

// 256 blocks (e, half): 128 rows each, 16 thr/row, shfl row-reduce -> bf16 A-frags
__global__ void __launch_bounds__(256) k_afrag(const float* __restrict__ teacher,
                                               const u8* __restrict__ mask_t,
                                               u16* __restrict__ af) {
    int e = blockIdx.x >> 1, h = blockIdx.x & 1;
    int t = threadIdx.x;
    int lane16 = t & 15;
    int f0 = lane16 * 8;
    #pragma unroll
    for (int it = 0; it < 8; it++) {
        int b = h * 128 + it * 16 + (t >> 4);
        float4 x0 = *(const float4*)&teacher[b * F + f0];
        float4 x1 = *(const float4*)&teacher[b * F + f0 + 4];
        const u8* mk = &mask_t[((size_t)e * B + b) * F + f0];
        float v[8];
        v[0] = mk[0] ? 0.f : x0.x; v[1] = mk[1] ? 0.f : x0.y;
        v[2] = mk[2] ? 0.f : x0.z; v[3] = mk[3] ? 0.f : x0.w;
        v[4] = mk[4] ? 0.f : x1.x; v[5] = mk[5] ? 0.f : x1.y;
        v[6] = mk[6] ? 0.f : x1.z; v[7] = mk[7] ? 0.f : x1.w;
        float ss = 0.f;
        #pragma unroll
        for (int j = 0; j < 8; j++) ss = fmaf(v[j], v[j], ss);
        ss += __shfl_xor(ss, 1); ss += __shfl_xor(ss, 2);
        ss += __shfl_xor(ss, 4); ss += __shfl_xor(ss, 8);
        float inv = 1.f / fmaxf(sqrtf(ss), 1e-12f);
        u16 o[8];
        #pragma unroll
        for (int j = 0; j < 8; j++) o[j] = f2bf(v[j] * inv);
        int bg = b >> 4, m = b & 15;
        int kb = f0 >> 5, quad = (f0 >> 3) & 3;
        int lane = quad * 16 + m;
        *(s8v*)&af[((((size_t)e * 16 + bg) * 4 + kb) * 64 + lane) * 8] = *(const s8v*)o;
    }
}

// per (e, 1024-q block): 1/(TAU*||masked neg col||)
__global__ void __launch_bounds__(256) k_invn(const float* __restrict__ neg,
                                              const u32* __restrict__ pn,
                                              float* __restrict__ invn) {
    __shared__ u32 lds[32 * 128];
    int e = blockIdx.x, t = threadIdx.x;
    int qblk = blockIdx.y;
    size_t base = ((size_t)e * QW + qblk * 32) * F;
    #pragma unroll
    for (int k = 0; k < 16; k++) lds[t + 256 * k] = pn[base + t + 256 * k];
    __syncthreads();
    int q0 = qblk * 1024 + t * 4;
    int qwl = (t * 4) >> 5;
    int sh = (t * 4) & 31;
    float s0 = 0.f, s1 = 0.f, s2 = 0.f, s3 = 0.f;
    #pragma unroll 4
    for (int f = 0; f < F; f++) {
        float4 v = *(const float4*)&neg[(size_t)f * Q + q0];
        u32 w = lds[qwl * 128 + f] >> sh;
        if (!(w & 1u)) s0 = fmaf(v.x, v.x, s0);
        if (!(w & 2u)) s1 = fmaf(v.y, v.y, s1);
        if (!(w & 4u)) s2 = fmaf(v.z, v.z, s2);
        if (!(w & 8u)) s3 = fmaf(v.w, v.w, s3);
    }
    float4 r;
    r.x = INV_TAU / fmaxf(sqrtf(s0), 1e-12f);
    r.y = INV_TAU / fmaxf(sqrtf(s1), 1e-12f);
    r.z = INV_TAU / fmaxf(sqrtf(s2), 1e-12f);
    r.w = INV_TAU / fmaxf(sqrtf(s3), 1e-12f);
    *(float4*)&invn[(size_t)e * Q + q0] = r;
}

// per (e, 64-q slab): build bf16 B fragments (masked, normalized) with coalesced
// float4 neg reads + LDS transpose -> 16B fragment dumps
__global__ void __launch_bounds__(256) k_bprep(const float* __restrict__ neg,
                                               const u32* __restrict__ pn,
                                               const float* __restrict__ invn,
                                               u16* __restrict__ bf) {
    __shared__ u16 lf[8192];               // 16 KB fragment tile
    __shared__ u32 pnl[2][128];
    __shared__ float invl[64];
    int e = blockIdx.x, qb = blockIdx.y, t = threadIdx.x;
    int q0 = qb * 64, qw0 = qb * 2;
    if (t < 128) pnl[0][t] = pn[((size_t)e * QW + qw0) * F + t];
    else pnl[1][t - 128] = pn[((size_t)e * QW + qw0 + 1) * F + t - 128];
    if (t < 16) *(float4*)&invl[t * 4] = *(const float4*)&invn[(size_t)e * Q + q0 + t * 4];
    __syncthreads();
    #pragma unroll
    for (int it = 0; it < 8; it++) {
        int idx = it * 256 + t;
        int f = idx >> 4, qq = (idx & 15) * 4;
        float4 x = *(const float4*)&neg[(size_t)f * Q + q0 + qq];
        int kb = f >> 5, quad = (f >> 3) & 3, j = f & 7;
        float xv[4] = {x.x, x.y, x.z, x.w};
        #pragma unroll
        for (int c = 0; c < 4; c++) {
            int ql = qq + c;
            u32 bit = (pnl[ql >> 5][f] >> (ql & 31)) & 1u;
            float v = bit ? 0.f : xv[c] * invl[ql];
            int qg = ql >> 4;
            int lane = quad * 16 + (ql & 15);
            lf[(((qg * 4 + kb) * 64) + lane) * 8 + j] = f2bf(v);
        }
    }
    __syncthreads();
    size_t gb = ((size_t)e * 256 + qb * 4) * 4 * 64 * 8;   // base of this slab's frags
    #pragma unroll
    for (int it = 0; it < 4; it++) {
        int s = it * 256 + t;                              // flat (qg*4+kb)*64+lane
        *(s8v*)&bf[gb + (size_t)s * 8] = *(const s8v*)&lf[s * 8];
    }
}

// Fused: per (e, 32-q slab): direct-load fragments, MFMA (8 tiles, acc[4][2] = 32 VGPR),
// exp, column softmax+entropy (boot), popc-reserved extraction of (q, exp) entries.
__global__ void __launch_bounds__(256) k_fused(
        const u16* __restrict__ af, const u16* __restrict__ bf,
        const u32* __restrict__ pb, const u32* __restrict__ ps,
        float* __restrict__ unc, uint2* __restrict__ ent_buf,
        int* __restrict__ cnt_buf, int e0) {
    __shared__ u32 bw[256], sw[256];                          // 2 KB
    __shared__ float sstat[4][32], cstat[4][32], estat[4][32];
    __shared__ float carr[32];
    __shared__ int sbase[256];

    int qb = blockIdx.x;                  // 0..127 (32-q slab == one mask word)
    int el = blockIdx.y, e = e0 + el;
    int t = threadIdx.x;
    int q0 = qb * 32;

    bw[t] = pb[((size_t)e * QW + qb) * B + t];
    sw[t] = ps[((size_t)e * QW + qb) * B + t];
    __syncthreads();

    // ---- MFMA: wave w covers b in [w*64, w*64+64), 2 qg columns ----
    int wave = t >> 6, lane = t & 63;
    int colb = lane & 15, quad = lane >> 4;
    const s8v* bfv = (const s8v*)&bf[((size_t)e * 256 + qb * 2) * 4 * 64 * 8];
    f32x4 acc[4][2];
    #pragma unroll
    for (int bgi = 0; bgi < 4; bgi++) {
        int bg = wave * 4 + bgi;
        s8v a[4];
        #pragma unroll
        for (int kb = 0; kb < 4; kb++)
            a[kb] = *(const s8v*)&af[((((size_t)e * 16 + bg) * 4 + kb) * 64 + lane) * 8];
        #pragma unroll
        for (int qg = 0; qg < 2; qg++) {
            f32x4 c4 = {0.f, 0.f, 0.f, 0.f};
            #pragma unroll
            for (int kb = 0; kb < 4; kb++) {
                s8v bv = bfv[(qg * 4 + kb) * 64 + lane];
                c4 = __builtin_amdgcn_mfma_f32_16x16x32_bf16(a[kb], bv, c4, 0, 0, 0);
            }
            acc[bgi][qg] = c4;
        }
    }

    // ---- exp in place (M = 0 safe: |sim*INV_TAU| <= ~5.2) ----
    #pragma unroll
    for (int bgi = 0; bgi < 4; bgi++)
        #pragma unroll
        for (int qg = 0; qg < 2; qg++)
            #pragma unroll
            for (int r = 0; r < 4; r++)
                acc[bgi][qg][r] = __expf(acc[bgi][qg][r]);

    // ---- column (boot) exp-sum + count ----
    float sloc[2] = {0.f, 0.f}, cloc[2] = {0.f, 0.f};
    #pragma unroll
    for (int bgi = 0; bgi < 4; bgi++) {
        int b0 = (wave * 4 + bgi) * 16 + quad * 4;
        uint4 w0 = *(const uint4*)&bw[b0];
        u32 W[4] = {w0.x, w0.y, w0.z, w0.w};
        #pragma unroll
        for (int r = 0; r < 4; r++)
            #pragma unroll
            for (int qg = 0; qg < 2; qg++) {
                if ((W[r] >> (qg * 16 + colb)) & 1u) {
                    sloc[qg] += acc[bgi][qg][r];
                    cloc[qg] += 1.f;
                }
            }
    }
    #pragma unroll
    for (int qg = 0; qg < 2; qg++) {
        sloc[qg] += __shfl_xor(sloc[qg], 16); sloc[qg] += __shfl_xor(sloc[qg], 32);
        cloc[qg] += __shfl_xor(cloc[qg], 16); cloc[qg] += __shfl_xor(cloc[qg], 32);
    }
    if (quad == 0)
        #pragma unroll
        for (int qg = 0; qg < 2; qg++) {
            sstat[wave][qg * 16 + colb] = sloc[qg];
            cstat[wave][qg * 16 + colb] = cloc[qg];
        }
    __syncthreads();
    float invS[2];
    #pragma unroll
    for (int qg = 0; qg < 2; qg++) {
        int c = qg * 16 + colb;
        float S = sstat[0][c] + sstat[1][c] + sstat[2][c] + sstat[3][c];
        invS[qg] = 1.f / fmaxf(S, 1e-30f);
    }
    if (wave == 0 && quad == 0)
        #pragma unroll
        for (int qg = 0; qg < 2; qg++) {
            int c = qg * 16 + colb;
            carr[c] = cstat[0][c] + cstat[1][c] + cstat[2][c] + cstat[3][c];
        }

    // ---- entropy (reuse exps) ----
    const float P0 = 1e-7f;
    const float C0 = 1.61180954e-6f;      // -P0*log(P0)
    float eloc[2] = {0.f, 0.f};
    #pragma unroll
    for (int bgi = 0; bgi < 4; bgi++) {
        int b0 = (wave * 4 + bgi) * 16 + quad * 4;
        uint4 w0 = *(const uint4*)&bw[b0];
        u32 W[4] = {w0.x, w0.y, w0.z, w0.w};
        #pragma unroll
        for (int r = 0; r < 4; r++)
            #pragma unroll
            for (int qg = 0; qg < 2; qg++) {
                if ((W[r] >> (qg * 16 + colb)) & 1u) {
                    float p = acc[bgi][qg][r] * invS[qg] + P0;
                    eloc[qg] -= p * __logf(p);
                } else {
                    eloc[qg] += C0;
                }
            }
    }
    #pragma unroll
    for (int qg = 0; qg < 2; qg++) {
        eloc[qg] += __shfl_xor(eloc[qg], 16); eloc[qg] += __shfl_xor(eloc[qg], 32);
    }
    if (quad == 0)
        #pragma unroll
        for (int qg = 0; qg < 2; qg++) estat[wave][qg * 16 + colb] = eloc[qg];

    // ---- extraction reservation (per-b popc) ----
    {
        int n = __popc(sw[t]);
        int base = 0;
        if (n) base = atomicAdd(&cnt_buf[el * B + t], n);
        sbase[t] = base;
    }
    __syncthreads();

    if (t < 32) {
        float tot = estat[0][t] + estat[1][t] + estat[2][t] + estat[3][t];
        atomicAdd(&unc[q0 + t], tot / fmaxf(carr[t], 1.f));
    }

    // ---- scatter compact (q, exp) entries ----
    #pragma unroll
    for (int bgi = 0; bgi < 4; bgi++) {
        int b0 = (wave * 4 + bgi) * 16 + quad * 4;
        uint4 s0 = *(const uint4*)&sw[b0];
        u32 S[4] = {s0.x, s0.y, s0.z, s0.w};
        #pragma unroll
        for (int r = 0; r < 4; r++) {
            #pragma unroll
            for (int qg = 0; qg < 2; qg++) {
                int bpos = qg * 16 + colb;
                u32 w = S[r];
                if ((w >> bpos) & 1u) {
                    int pos = sbase[b0 + r] + __popc(w & ((1u << bpos) - 1u));
                    if (pos < CAP) {
                        uint2 en;
                        en.x = (unsigned)(q0 + bpos);
                        en.y = __builtin_bit_cast(unsigned, acc[bgi][qg][r]);
                        ent_buf[((size_t)(el * B + b0 + r)) * CAP + pos] = en;
                    }
                }
            }
        }
    }
}

// grid (b, z): z-half of ensembles -> row softmax scatter into slab z
__global__ void __launch_bounds__(512) k_scores(
        const uint2* __restrict__ ent_buf, const int* __restrict__ cnt_buf,
        float* __restrict__ sacc, float* __restrict__ cacc, int ecnt) {
    __shared__ float srow[Q];
    __shared__ float crow[Q];
    __shared__ int cl[64];
    int b = blockIdx.x, z = blockIdx.y, t = threadIdx.x;
    int half = (ecnt + 1) >> 1;
    int el0 = z * half;
    int nel = ecnt - el0; if (nel > half) nel = half; if (nel < 0) nel = 0;
    #pragma unroll
    for (int j = 0; j < 8; j++) { srow[t + 512 * j] = 0.f; crow[t + 512 * j] = 0.f; }
    if (t < nel) {
        int c = cnt_buf[(el0 + t) * B + b];
        cl[t] = (c > CAP) ? CAP : c;
    }
    __syncthreads();
    int wave = t >> 6, lane = t & 63;
    for (int i = wave; i < nel; i += 8) {
        int c = cl[i];
        if (c == 0) continue;
        const uint2* p = ent_buf + (size_t)((el0 + i) * B + b) * CAP;
        uint2 ev[4]; int ne = 0;
        float s = 0.f;
        for (int k = lane; k < c; k += 64) {
            ev[ne] = p[k];
            s += __builtin_bit_cast(float, ev[ne].y);
            ne++;
        }
        #pragma unroll
        for (int off = 32; off > 0; off >>= 1) s += __shfl_xor(s, off);
        float iS = 1.f / fmaxf(s, 1e-30f);
        for (int k = 0; k < ne; k++) {
            atomicAdd(&srow[ev[k].x], __builtin_bit_cast(float, ev[k].y) * iS);
            atomicAdd(&crow[ev[k].x], 1.f);
        }
    }
    __syncthreads();
    float* sa = sacc + (size_t)z * B * Q;
    float* ca = cacc + (size_t)z * B * Q;
    #pragma unroll
    for (int j = 0; j < 8; j++) {
        int q = t + 512 * j;
        sa[(size_t)b * Q + q] += srow[q];
        ca[(size_t)b * Q + q] += crow[q];
    }
}

// (b, seg) grid: logits slab of 1024 q; seg 0 also writes pos logit
__global__ void k_logits(const float* __restrict__ query, const float* __restrict__ key,
                         const float* __restrict__ neg, float* __restrict__ out) {
    __shared__ float qrow[F];
    __shared__ float red[256];
    int b = blockIdx.x, seg = blockIdx.y, t = threadIdx.x;
    if (t < F) qrow[t] = query[b * F + t];
    __syncthreads();
    int q0 = seg * 1024 + t * 4;
    float4 acc = make_float4(0.f, 0.f, 0.f, 0.f);
    for (int f = 0; f < F; f++) {
        float a = qrow[f];
        float4 v = *(const float4*)&neg[(size_t)f * Q + q0];
        acc.x = fmaf(a, v.x, acc.x);
        acc.y = fmaf(a, v.y, acc.y);
        acc.z = fmaf(a, v.z, acc.z);
        acc.w = fmaf(a, v.w, acc.w);
    }
    float* row = out + O_LOGITS + (size_t)b * (Q + 1);
    row[1 + q0]     = acc.x * INV_TAU;
    row[1 + q0 + 1] = acc.y * INV_TAU;
    row[1 + q0 + 2] = acc.z * INV_TAU;
    row[1 + q0 + 3] = acc.w * INV_TAU;
    if (seg == 0) {
        float pp = (t < F) ? qrow[t] * key[b * F + t] : 0.f;
        red[t] = pp;
        __syncthreads();
        for (int s = 128; s > 0; s >>= 1) { if (t < s) red[t] += red[t + s]; __syncthreads(); }
        if (t == 0) row[0] = red[0] * INV_TAU;
    }
}

// block per b: moco part (full-row LSE - z0) and neg-only LSE
__global__ void k_rowstats(const float* __restrict__ out, float* __restrict__ moco_part,
                           float* __restrict__ nlse) {
    __shared__ float red[256];
    int b = blockIdx.x, t = threadIdx.x;
    const float* row = out + O_LOGITS + (size_t)b * (Q + 1);
    float m = -INFINITY, mn = -INFINITY;
    for (int j = 0; j < 17; j++) {
        int i = t + 256 * j;
        if (i < Q + 1) { float zz = row[i]; m = fmaxf(m, zz); if (i >= 1) mn = fmaxf(mn, zz); }
    }
    red[t] = m; __syncthreads();
    for (int s = 128; s > 0; s >>= 1) { if (t < s) red[t] = fmaxf(red[t], red[t + s]); __syncthreads(); }
    float M = red[0]; __syncthreads();
    red[t] = mn; __syncthreads();
    for (int s = 128; s > 0; s >>= 1) { if (t < s) red[t] = fmaxf(red[t], red[t + s]); __syncthreads(); }
    float Mn = red[0]; __syncthreads();
    float s1 = 0.f, s2 = 0.f;
    for (int j = 0; j < 17; j++) {
        int i = t + 256 * j;
        if (i < Q + 1) { float zz = row[i]; s1 += expf(zz - M); if (i >= 1) s2 += expf(zz - Mn); }
    }
    red[t] = s1; __syncthreads();
    for (int s = 128; s > 0; s >>= 1) { if (t < s) red[t] += red[t + s]; __syncthreads(); }
    float S = red[0]; __syncthreads();
    red[t] = s2; __syncthreads();
    for (int s = 128; s > 0; s >>= 1) { if (t < s) red[t] += red[t + s]; __syncthreads(); }
    float Sn = red[0];
    if (t == 0) { moco_part[b] = M + logf(S) - row[0]; nlse[b] = Mn + logf(Sn); }
}

// normalize unc (/E), bitonic sort 4096, median per np.quantile 'linear'
__global__ void k_median(float* __restrict__ unc, float* __restrict__ ubp) {
    __shared__ float sd[4096];
    int t = threadIdx.x;
    #pragma unroll
    for (int j = 0; j < 4; j++) {
        int q = t + 1024 * j;
        float u = unc[q] * (1.f / 128.f);
        unc[q] = u; sd[q] = u;
    }
    __syncthreads();
    for (int k = 2; k <= 4096; k <<= 1) {
        for (int j = k >> 1; j > 0; j >>= 1) {
            #pragma unroll
            for (int base = 0; base < 4; base++) {
                int i = t + 1024 * base;
                int ixj = i ^ j;
                if (ixj > i) {
                    bool up = ((i & k) == 0);
                    float x = sd[i], y = sd[ixj];
                    if ((x > y) == up) { sd[i] = y; sd[ixj] = x; }
                }
            }
            __syncthreads();
        }
    }
    if (t == 0) { float a = sd[2047], b2 = sd[2048]; ubp[0] = a + 0.5f * (b2 - a); }
}

// per (b, mode): argmax of scores among allowed q (lowest-index ties), mask + loss
__global__ void k_select(float* __restrict__ out, const float* __restrict__ sacc,
                         const float* __restrict__ cacc,
                         const float* __restrict__ unc, const float* __restrict__ ubp,
                         const float* __restrict__ nlse, float* __restrict__ easy_part,
                         float* __restrict__ hard_part) {
    __shared__ float rv[256];
    __shared__ int ri[256];
    __shared__ int bshare;
    int b = blockIdx.x, mode = blockIdx.y, t = threadIdx.x;
    float ub = ubp[0];
    float bv = -INFINITY; int bidx = Q;
    #pragma unroll
    for (int j = 0; j < 16; j++) {
        int q = t + 256 * j;
        float u = unc[q];
        bool ok = (mode == 0) ? (u <= ub) : (u >= ub);
        if (ok) {
            size_t ix = (size_t)b * Q + q;
            float s = sacc[ix] + sacc[(size_t)B * Q + ix];
            float c = cacc[ix] + cacc[(size_t)B * Q + ix];
            float v = s / fmaxf(c, 1.f);
            if (v > bv || (v == bv && q < bidx)) { bv = v; bidx = q; }
        }
    }
    rv[t] = bv; ri[t] = bidx; __syncthreads();
    for (int s = 128; s > 0; s >>= 1) {
        if (t < s) {
            float v2 = rv[t + s]; int i2 = ri[t + s];
            if (v2 > rv[t] || (v2 == rv[t] && i2 < ri[t])) { rv[t] = v2; ri[t] = i2; }
        }
        __syncthreads();
    }
    if (t == 0) {
        int best = ri[0]; bshare = best;
        float zz = out[O_LOGITS + (size_t)b * (Q + 1) + 1 + best];
        float loss = nlse[b] - zz;
        (mode == 0 ? easy_part : hard_part)[b] = loss;
    }
    __syncthreads();
    int best = bshare;
    float* mrow = out + (mode == 0 ? O_EMASK : O_HMASK) + (size_t)b * Q;
    #pragma unroll
    for (int j = 0; j < 16; j++) { int q = t + 256 * j; mrow[q] = (q == best) ? 1.f : 0.f; }
}

__global__ void k_scalars(const float* __restrict__ moco, const float* __restrict__ easyp,
                          const float* __restrict__ hardp, float* __restrict__ out) {
    __shared__ float red[256];
    int t = threadIdx.x;
    red[t] = moco[t]; __syncthreads();
    for (int s = 128; s > 0; s >>= 1) { if (t < s) red[t] += red[t + s]; __syncthreads(); }
    if (t == 0) out[O_MOCO] = red[0] / 256.f;
    __syncthreads();
    red[t] = easyp[t]; __syncthreads();
    for (int s = 128; s > 0; s >>= 1) { if (t < s) red[t] += red[t + s]; __syncthreads(); }
    if (t == 0) out[O_ELOSS] = red[0] / 256.f;
    __syncthreads();
    red[t] = hardp[t]; __syncthreads();
    for (int s = 128; s > 0; s >>= 1) { if (t < s) red[t] += red[t + s]; __syncthreads(); }
    if (t == 0) out[O_HLOSS] = red[0] / 256.f;
}

extern "C" void kernel_launch(void* const* d_in, const int* in_sizes, int n_in,
                              void* d_out, int out_size, void* d_ws, size_t ws_size,
                              hipStream_t stream) {
    const float* query   = (const float*)d_in[0];
    const float* key     = (const float*)d_in[1];
    const float* teacher = (const float*)d_in[2];
    const float* neg     = (const float*)d_in[3];
    const u8* mask_t     = (const u8*)d_in[4];
    const u8* mask_n     = (const u8*)d_in[5];
    const u8* score_mask = (const u8*)d_in[6];
    const u8* boot_mask  = (const u8*)d_in[7];
    float* out = (float*)d_out;
    float* ws  = (float*)d_ws;

    long ws_floats = (long)(ws_size / 4);
    int Ec = (int)((ws_floats - (long)W_ENT) / (long)(B * CAP * 2));
    if (Ec > E) Ec = E;
    if (Ec < 1) Ec = 1;

    u16* af = (u16*)(ws + W_AF);
    u32* pb = (u32*)(ws + W_PB);
    u32* ps = (u32*)(ws + W_PS);
    u32* pn = (u32*)(ws + W_PN);
    u16* bfr = (u16*)(ws + W_BF);
    int* cnt_buf = (int*)(ws + W_CNTB);
    uint2* ent_buf = (uint2*)(ws + W_ENT);

    // zero scores x2 + cnt x2 + unc + cnt_buf (contiguous 4231168 floats)
    k_zero<<<NZERO / 1024, 256, 0, stream>>>((float4*)(ws + W_SCORES));
    k_pack<<<dim3((E * B) / 64, Q / 512, 3), 256, 0, stream>>>(
        boot_mask, score_mask, mask_n, pb, ps, pn);
    k_afrag<<<E * 2, 256, 0, stream>>>(teacher, mask_t, af);
    k_invn<<<dim3(E, 4), 256, 0, stream>>>(neg, pn, ws + W_INVN);
    k_bprep<<<dim3(E, Q / 64), 256, 0, stream>>>(neg, pn, ws + W_INVN, bfr);
    k_logits<<<dim3(B, 4), 256, 0, stream>>>(query, key, neg, out);
    k_rowstats<<<B, 256, 0, stream>>>(out, ws + W_MOCO, ws + W_NLSE);

    for (int e0 = 0; e0 < E; e0 += Ec) {
        int ecnt = (E - e0 < Ec) ? (E - e0) : Ec;
        if (e0 > 0)
            k_zero<<<32, 256, 0, stream>>>((float4*)(ws + W_CNTB));  // cnt_buf
        k_fused<<<dim3(Q / 32, ecnt), 256, 0, stream>>>(
            af, bfr, pb, ps, ws + W_UNC, ent_buf, cnt_buf, e0);
        k_scores<<<dim3(B, 2), 512, 0, stream>>>(ent_buf, cnt_buf,
                                                 ws + W_SCORES, ws + W_CNT, ecnt);
    }

    k_median<<<1, 1024, 0, stream>>>(ws + W_UNC, ws + W_UB);
    k_select<<<dim3(B, 2), 256, 0, stream>>>(out, ws + W_SCORES, ws + W_CNT,
                                             ws + W_UNC, ws + W_UB,
                                             ws + W_NLSE, ws + W_EASY, ws + W_HARD);
    k_scalars<<<1, 256, 0, stream>>>(ws + W_MOCO, ws + W_EASY, ws + W_HARD, out);
}